// Round 10
// baseline (564.763 us; speedup 1.0000x reference)
//
#include <hip/hip_runtime.h>

typedef unsigned short ushort_t;
typedef unsigned long long u64;
typedef short short8 __attribute__((ext_vector_type(8)));
typedef float f32x4 __attribute__((ext_vector_type(4)));

#define B_   32
#define C_   64
#define T_   12
#define N_   1024
#define KS_  3
#define KC_  3072
#define RPB  768
#define NT_  48          // K-tiles of 64
#define BM2  128
#define BN2  128
#define LBUF 32768       // BYTES per LDS buffer: A 16384 + B 16384
#define ABY2 16384       // A region bytes (2 planes x 128 rows x 64 B)

__device__ __forceinline__ float bf2f(ushort_t u) {
  union { unsigned u; float f; } v; v.u = ((unsigned)u) << 16; return v.f;
}
__device__ __forceinline__ ushort_t f2bf(float f) {
  union { float f; unsigned u; } v; v.f = f;
  unsigned r = v.u + 0x7FFFu + ((v.u >> 16) & 1u);
  return (ushort_t)(r >> 16);
}

__device__ __forceinline__ void gload16(const ushort_t* g, ushort_t* l) {
  __builtin_amdgcn_global_load_lds(
      (const __attribute__((address_space(1))) unsigned int*)g,
      (__attribute__((address_space(3))) unsigned int*)l, 16, 0, 0);
}

// ---------- prep: thA[l][k][o][i] = bf16(theta_l[i][o][k]) ----------
__global__ void prep_th(const float* __restrict__ th1, const float* __restrict__ th2,
                        ushort_t* __restrict__ out) {
  int id = blockIdx.x * 256 + threadIdx.x;          // 2*3*64*64 = 24576
  if (id >= 24576) return;
  int l = id / 12288, rem = id % 12288;
  int k = rem / 4096;
  int o = (rem >> 6) & 63;
  int i = rem & 63;
  const float* th = l ? th2 : th1;
  out[id] = f2bf(th[(i * 64 + o) * 3 + k]);
}

// ---------- prep: Bt[n][k*1024+m] = bf16(Lk[k][n][m])  (row-major, K-contiguous) ----------
__global__ void prep_bt(const float* __restrict__ Lk, ushort_t* __restrict__ Bt) {
  int id = blockIdx.x * 256 + threadIdx.x;
  int k = id >> 17, rem = id & 131071;
  int n = rem >> 7, mc = rem & 127;
  int m = mc << 3;
  const float* src = Lk + ((k * N_ + n) * N_ + m);
  float4 v0 = *(const float4*)src;
  float4 v1 = *(const float4*)(src + 4);
  short8 o8;
  o8[0] = (short)f2bf(v0.x); o8[1] = (short)f2bf(v0.y);
  o8[2] = (short)f2bf(v0.z); o8[3] = (short)f2bf(v0.w);
  o8[4] = (short)f2bf(v1.x); o8[5] = (short)f2bf(v1.y);
  o8[6] = (short)f2bf(v1.z); o8[7] = (short)f2bf(v1.w);
  *(short8*)&Bt[n * KC_ + k * N_ + m] = o8;
}

// ---------- MFMA channel mix (unchanged) ----------
template<int IN_BF16>
__global__ __launch_bounds__(256, 2)
void mix_mfma(const void* __restrict__ in, const ushort_t* __restrict__ thA,
              ushort_t* __restrict__ Y, int b0) {
  const int bid = blockIdx.x;           // nb*48: [bt][mq]
  const int mq = bid & 3;
  const int bt = bid >> 2;              // bl*12 + t
  const int bl = bt / 12, t = bt % 12;
  const int b = b0 + bl;
  const int tid = threadIdx.x;
  const int wv = tid >> 6, lane = tid & 63;
  const int l15 = lane & 15, l4 = lane >> 4;
  const int m0 = mq * 256 + wv * 64;

  const ushort_t* xg_b = (const ushort_t*)in;
  const float*    xg_f = (const float*)in;

  short8 bfr[4][2];
  #pragma unroll
  for (int mf = 0; mf < 4; ++mf) {
    const int m = m0 + mf * 16 + l15;
    #pragma unroll
    for (int ks = 0; ks < 2; ++ks) {
      #pragma unroll
      for (int j = 0; j < 8; ++j) {
        const int i = ks * 32 + l4 * 8 + j;
        const size_t adr = ((size_t)(b * C_ + i) * T_ + t) * N_ + m;
        ushort_t v = IN_BF16 ? xg_b[adr] : f2bf(xg_f[adr]);
        bfr[mf][ks][j] = (short)v;
      }
    }
  }

  const size_t rbase = (size_t)(bt * C_);
  #pragma unroll
  for (int k = 0; k < 3; ++k) {
    short8 afr[4][2];
    #pragma unroll
    for (int of = 0; of < 4; ++of)
      #pragma unroll
      for (int ks = 0; ks < 2; ++ks)
        afr[of][ks] = *(const short8*)&thA[(size_t)(k * 64 + of * 16 + l15) * 64 + ks * 32 + l4 * 8];

    f32x4 acc[4][4] = {};
    #pragma unroll
    for (int ks = 0; ks < 2; ++ks)
      #pragma unroll
      for (int of = 0; of < 4; ++of)
        #pragma unroll
        for (int mf = 0; mf < 4; ++mf)
          acc[of][mf] = __builtin_amdgcn_mfma_f32_16x16x32_bf16(afr[of][ks], bfr[mf][ks], acc[of][mf], 0, 0, 0);

    #pragma unroll
    for (int of = 0; of < 4; ++of)
      #pragma unroll
      for (int mf = 0; mf < 4; ++mf)
        #pragma unroll
        for (int r = 0; r < 4; ++r) {
          const int o = of * 16 + l4 * 4 + r;
          Y[(rbase + o) * KC_ + k * N_ + m0 + mf * 16 + l15] = f2bf(acc[of][mf][r]);
        }
  }
}

// ---------- 128x128-tile GEMM, 2 blocks/CU, r4-style phased schedule ----------
// LDS per buffer (32768 B): A [ks:2][row:128][64B] (16384) then B [ks:2][row:128][64B].
// Swizzle: stored col-byte = logical ^ (((row>>3)&1)<<5); applied on global source
// (write side) and on ds_read address (read side) — same involution as r4 (proven).
// 4 waves (2M x 2N), wave-tile 64x64, acc[4][4]. 2 phases/K-tile (one per ksub):
//   ph0(u): read ks0 frags (4A+4B); stage A2,A3,B2,B3(u+1)  [plane1 of buf[(u+1)&1],
//           last read ph1(u-1)+barrier]; barrier; 16 MFMA; barrier.
//   ph1(u): read ks1 frags;          stage A0,A1,B0,B1(u+2)  [plane0 of buf[u&1],
//           last read ph0(u)+barrier]; vmcnt(4) [outstanding = {u+1 last half(4),
//           u+2 first half(4)} -> proves tile u+1 complete]; barrier; 16 MFMA; barrier.
// Prologue: tile0 (8 units) + tile1 first half (4) + vmcnt(4). Tail: vmcnt(0).

#define MFMA16B()                                                                \
  _Pragma("unroll") for (int m_ = 0; m_ < 4; ++m_)                               \
    _Pragma("unroll") for (int n_ = 0; n_ < 4; ++n_)                             \
      acc[m_][n_] = __builtin_amdgcn_mfma_f32_16x16x32_bf16(af[m_], bf[n_], acc[m_][n_], 0, 0, 0);

#define STAGE_A(kt, j) gload16(gA##j + (size_t)(kt) * 64,                        \
    (ushort_t*)(lp + (((kt) & 1) ? LBUF : 0) + (j) * 4096 + wofs))
#define STAGE_B(kt, j) gload16(gB##j + (size_t)(kt) * 64,                        \
    (ushort_t*)(lp + (((kt) & 1) ? LBUF : 0) + ABY2 + (j) * 4096 + wofs))

#define LD8(p) (*(const short8*)(p))

template<int RES_BF16>
__global__ __launch_bounds__(256, 2)
void gemm2b(const ushort_t* __restrict__ Y, const ushort_t* __restrict__ Bt,
            const void* __restrict__ res, const float* __restrict__ bias,
            ushort_t* __restrict__ outb, int batch0) {
  // bijective XCD swizzle; gridDim.x = 48*nb is always a multiple of 8
  const int nwg = gridDim.x;
  int orig = blockIdx.x;
  int q8 = nwg >> 3;
  int wg = (orig & 7) * q8 + (orig >> 3);
  const int mtile = wg >> 3, ntile = wg & 7;

  const int tid = threadIdx.x;
  const int wid = tid >> 6, lane = tid & 63;
  const int wm = wid >> 1, wn = wid & 1;
  const int l15 = lane & 15, l4 = lane >> 4;

  __shared__ ushort_t LDSU[LBUF];   // 65536 bytes total (2 buffers)
  char* lp = (char*)LDSU;

  const int row0 = mtile * BM2;
  const int n0 = ntile * BN2;
  const int wofs = wid * 1024;

  // staging source pointers (per-lane, swizzle pre-applied on global col)
  // unit j covers virtual rows 64j..64j+63 (plane-major: vrow<128 -> ks0, else ks1)
  const int lam = lane >> 2, lc = lane & 3;
  const ushort_t *gA0, *gA1, *gA2, *gA3, *gB0, *gB1, *gB2, *gB3;
  {
    int p, s, row, colel;
    #define SRC_INIT(dst, base, b0_, j)                                          \
      p = (j) * 64 + wid * 16 + lam; s = p >> 7; row = p & 127;                  \
      colel = (lc * 8) ^ (((row >> 3) & 1) << 4);                                \
      dst = base + (size_t)((b0_) + row) * KC_ + s * 32 + colel;
    SRC_INIT(gA0, Y,  row0, 0) SRC_INIT(gA1, Y,  row0, 1)
    SRC_INIT(gA2, Y,  row0, 2) SRC_INIT(gA3, Y,  row0, 3)
    SRC_INIT(gB0, Bt, n0,   0) SRC_INIT(gB1, Bt, n0,   1)
    SRC_INIT(gB2, Bt, n0,   2) SRC_INIT(gB3, Bt, n0,   3)
    #undef SRC_INIT
  }

  // read-side lane byte bases (swizzle XOR on col)
  const int swz = ((l15 >> 3) & 1) << 5;
  const int a_base = (wm * 16 + l15) * 64 + ((l4 * 16) ^ swz);
  const int b_base = ABY2 + (wn * 16 + l15) * 64 + ((l4 * 16) ^ swz);

  // prologue: tile0 all 8 units; tile1 first half (A0,A1,B0,B1)
  STAGE_A(0, 0); STAGE_A(0, 1); STAGE_A(0, 2); STAGE_A(0, 3);
  STAGE_B(0, 0); STAGE_B(0, 1); STAGE_B(0, 2); STAGE_B(0, 3);
  STAGE_A(1, 0); STAGE_A(1, 1); STAGE_B(1, 0); STAGE_B(1, 1);
  asm volatile("s_waitcnt vmcnt(4)" ::: "memory");   // tile0 landed
  __builtin_amdgcn_sched_barrier(0);
  __builtin_amdgcn_s_barrier();

  f32x4 acc[4][4] = {};

  for (int u = 0; u < NT_; ++u) {
    const char* abp = lp + ((u & 1) ? LBUF : 0) + a_base;
    const char* bbp = lp + ((u & 1) ? LBUF : 0) + b_base;

    { // phase 0: ks0 reads + MFMA; stage plane1 of tile u+1
      short8 af[4], bf[4];
      #pragma unroll
      for (int f = 0; f < 4; ++f) af[f] = LD8(abp + f * 2048);
      #pragma unroll
      for (int f = 0; f < 4; ++f) bf[f] = LD8(bbp + f * 2048);
      if (u + 1 < NT_) { STAGE_A(u + 1, 2); STAGE_A(u + 1, 3);
                         STAGE_B(u + 1, 2); STAGE_B(u + 1, 3); }
      __builtin_amdgcn_s_barrier();
      __builtin_amdgcn_s_setprio(1);
      MFMA16B()
      __builtin_amdgcn_s_setprio(0);
      __builtin_amdgcn_s_barrier();
    }
    { // phase 1: ks1 reads + MFMA; stage plane0 of tile u+2; counted vmcnt
      short8 af[4], bf[4];
      #pragma unroll
      for (int f = 0; f < 4; ++f) af[f] = LD8(abp + 8192 + f * 2048);
      #pragma unroll
      for (int f = 0; f < 4; ++f) bf[f] = LD8(bbp + 8192 + f * 2048);
      if (u + 2 < NT_) {
        STAGE_A(u + 2, 0); STAGE_A(u + 2, 1);
        STAGE_B(u + 2, 0); STAGE_B(u + 2, 1);
        asm volatile("s_waitcnt vmcnt(4)" ::: "memory");  // tile u+1 complete
      } else {
        asm volatile("s_waitcnt vmcnt(0)" ::: "memory");  // tail drain
      }
      __builtin_amdgcn_sched_barrier(0);
      __builtin_amdgcn_s_barrier();
      __builtin_amdgcn_s_setprio(1);
      MFMA16B()
      __builtin_amdgcn_s_setprio(0);
      __builtin_amdgcn_s_barrier();
    }
  }

  // epilogue: bias + residual + relu, bf16 store
  const float*    resf = (const float*)res;
  const ushort_t* resb = (const ushort_t*)res;
  const int gb = batch0 + mtile / 6;
  const int rowb0 = (mtile % 6) * BM2;
  const int colb = n0 + wn * 16 + l15;
  #pragma unroll
  for (int mf = 0; mf < 4; ++mf) {
    #pragma unroll
    for (int r = 0; r < 4; ++r) {
      int rl = mf * 32 + wm * 16 + l4 * 4 + r;
      int rowb = rowb0 + rl;
      int t = rowb >> 6, o = rowb & 63;
      float bs = bias[o];
      size_t base = ((size_t)(gb * C_ + o) * T_ + t) * N_;
      #pragma unroll
      for (int nf = 0; nf < 4; ++nf) {
        int col = colb + nf * 32;
        float rv = RES_BF16 ? bf2f(resb[base + col]) : resf[base + col];
        float v = acc[mf][nf][r] + bs + rv;
        v = fmaxf(v, 0.0f);
        outb[base + col] = f2bf(v);
      }
    }
  }
}

// ---------- FC: out[b,t,n,o2] = sum_o fw[o2,o]*x2[b,o,t,n] + fb[o2] ----------
__global__ __launch_bounds__(256, 2)
void fc_kernel(const ushort_t* __restrict__ x2, const float* __restrict__ fw,
               const float* __restrict__ fb, float* __restrict__ out) {
  int bid = blockIdx.x;
  int nt = bid & 15, btid = bid >> 4;
  int t = btid % 12, b = btid / 12;
  int n0 = nt << 6;
  int tid = threadIdx.x;
  __shared__ float xt[64 * 64];
  __shared__ float wl[64 * 64];
  #pragma unroll
  for (int j = 0; j < 2; ++j) {
    int c = tid + j * 256;
    int row = c >> 3, col = (c & 7) << 3;
    short8 v = *(const short8*)&x2[((b * C_ + row) * T_ + t) * N_ + n0 + col];
    #pragma unroll
    for (int q = 0; q < 8; ++q) xt[row * 64 + col + q] = bf2f((ushort_t)v[q]);
  }
  #pragma unroll
  for (int j = 0; j < 4; ++j) {
    int c = tid + j * 256;
    int o2 = c >> 4, o4 = (c & 15) << 2;
    float4 v = *(const float4*)&fw[o2 * 64 + o4];
    wl[(o4 + 0) * 64 + o2] = v.x; wl[(o4 + 1) * 64 + o2] = v.y;
    wl[(o4 + 2) * 64 + o2] = v.z; wl[(o4 + 3) * 64 + o2] = v.w;
  }
  __syncthreads();
  int p = tid & 31, ng = tid >> 5;
  float a0[8] = {}, a1[8] = {};
  for (int o = 0; o < 64; ++o) {
    float w0 = wl[o * 64 + p], w1 = wl[o * 64 + p + 32];
    float4 xa = *(const float4*)&xt[o * 64 + ng * 8];
    float4 xb = *(const float4*)&xt[o * 64 + ng * 8 + 4];
    float xv[8] = {xa.x, xa.y, xa.z, xa.w, xb.x, xb.y, xb.z, xb.w};
    #pragma unroll
    for (int j = 0; j < 8; ++j) { a0[j] = fmaf(w0, xv[j], a0[j]); a1[j] = fmaf(w1, xv[j], a1[j]); }
  }
  float fb0 = fb[p], fb1 = fb[p + 32];
  int obase = (b * T_ + t) * N_ + n0 + ng * 8;
  #pragma unroll
  for (int j = 0; j < 8; ++j) {
    out[(obase + j) * 64 + p]      = a0[j] + fb0;
    out[(obase + j) * 64 + p + 32] = a1[j] + fb1;
  }
}

extern "C" void kernel_launch(void* const* d_in, const int* in_sizes, int n_in,
                              void* d_out, int out_size, void* d_ws, size_t ws_size,
                              hipStream_t stream) {
  const float* x   = (const float*)d_in[0];
  const float* Lk  = (const float*)d_in[1];
  const float* th1 = (const float*)d_in[2];
  const float* b1  = (const float*)d_in[3];
  const float* th2 = (const float*)d_in[4];
  const float* b2  = (const float*)d_in[5];
  const float* fcw = (const float*)d_in[6];
  const float* fcb = (const float*)d_in[7];

  char* ws = (char*)d_ws;
  size_t off = 0;
  auto alloc = [&](size_t bytes) { size_t p = off; off += (bytes + 255) & ~(size_t)255; return p; };
  size_t oBt = alloc((size_t)KC_ * N_ * 2);
  size_t oTh = alloc((size_t)2 * 3 * 64 * 64 * 2);
  size_t oX2 = alloc((size_t)B_ * C_ * T_ * N_ * 2);
  size_t perB = (size_t)RPB * KC_ * 2;
  size_t avail = ws_size > off ? ws_size - off : 0;
  int NB = (int)(avail / perB);
  if (NB > B_) NB = B_;
  if (NB < 1) NB = 1;

  ushort_t* Bt = (ushort_t*)(ws + oBt);
  ushort_t* Th = (ushort_t*)(ws + oTh);
  ushort_t* X2 = (ushort_t*)(ws + oX2);
  ushort_t* Yb = (ushort_t*)(ws + off);
  ushort_t* X1 = (ushort_t*)d_out;

  prep_th<<<96, 256, 0, stream>>>(th1, th2, Th);
  prep_bt<<<1536, 256, 0, stream>>>(Lk, Bt);

  for (int b0 = 0; b0 < B_; b0 += NB) {
    int nb = (b0 + NB <= B_) ? NB : (B_ - b0);
    mix_mfma<0><<<nb * 48, 256, 0, stream>>>((const void*)x, Th, Yb, b0);
    gemm2b<0><<<dim3(48 * nb), 256, 0, stream>>>(Yb, Bt, (const void*)x, b1, X1, b0);
  }
  for (int b0 = 0; b0 < B_; b0 += NB) {
    int nb = (b0 + NB <= B_) ? NB : (B_ - b0);
    mix_mfma<1><<<nb * 48, 256, 0, stream>>>((const void*)X1, Th + 12288, Yb, b0);
    gemm2b<1><<<dim3(48 * nb), 256, 0, stream>>>(Yb, Bt, (const void*)X1, b2, X2, b0);
  }
  fc_kernel<<<32 * 12 * 16, 256, 0, stream>>>(X2, fcw, fcb, (float*)d_out);
}

// Round 11
// 556.312 us; speedup vs baseline: 1.0152x; 1.0152x over previous
//
#include <hip/hip_runtime.h>

typedef unsigned short ushort_t;
typedef unsigned long long u64;
typedef short short8 __attribute__((ext_vector_type(8)));
typedef float f32x4 __attribute__((ext_vector_type(4)));

#define B_   32
#define C_   64
#define T_   12
#define N_   1024
#define KS_  3
#define KC_  3072
#define RPB  768
#define NT_  48          // K-tiles of 64
#define LB3  65536       // bytes per LDS buffer: A 32768 + B 32768

__device__ __forceinline__ float bf2f(ushort_t u) {
  union { unsigned u; float f; } v; v.u = ((unsigned)u) << 16; return v.f;
}
__device__ __forceinline__ ushort_t f2bf(float f) {
  union { float f; unsigned u; } v; v.f = f;
  unsigned r = v.u + 0x7FFFu + ((v.u >> 16) & 1u);
  return (ushort_t)(r >> 16);
}

__device__ __forceinline__ void gload16(const ushort_t* g, ushort_t* l) {
  __builtin_amdgcn_global_load_lds(
      (const __attribute__((address_space(1))) unsigned int*)g,
      (__attribute__((address_space(3))) unsigned int*)l, 16, 0, 0);
}

// ---------- prep: thA[l][k][o][i] = bf16(theta_l[i][o][k]) ----------
__global__ void prep_th(const float* __restrict__ th1, const float* __restrict__ th2,
                        ushort_t* __restrict__ out) {
  int id = blockIdx.x * 256 + threadIdx.x;          // 2*3*64*64 = 24576
  if (id >= 24576) return;
  int l = id / 12288, rem = id % 12288;
  int k = rem / 4096;
  int o = (rem >> 6) & 63;
  int i = rem & 63;
  const float* th = l ? th2 : th1;
  out[id] = f2bf(th[(i * 64 + o) * 3 + k]);
}

// ---------- prep: Bt[n][k*1024+m] = bf16(Lk[k][n][m])  (row-major, K-contiguous) ----------
__global__ void prep_bt(const float* __restrict__ Lk, ushort_t* __restrict__ Bt) {
  int id = blockIdx.x * 256 + threadIdx.x;
  int k = id >> 17, rem = id & 131071;
  int n = rem >> 7, mc = rem & 127;
  int m = mc << 3;
  const float* src = Lk + ((k * N_ + n) * N_ + m);
  float4 v0 = *(const float4*)src;
  float4 v1 = *(const float4*)(src + 4);
  short8 o8;
  o8[0] = (short)f2bf(v0.x); o8[1] = (short)f2bf(v0.y);
  o8[2] = (short)f2bf(v0.z); o8[3] = (short)f2bf(v0.w);
  o8[4] = (short)f2bf(v1.x); o8[5] = (short)f2bf(v1.y);
  o8[6] = (short)f2bf(v1.z); o8[7] = (short)f2bf(v1.w);
  *(short8*)&Bt[n * KC_ + k * N_ + m] = o8;
}

// ---------- MFMA channel mix (unchanged) ----------
template<int IN_BF16>
__global__ __launch_bounds__(256, 2)
void mix_mfma(const void* __restrict__ in, const ushort_t* __restrict__ thA,
              ushort_t* __restrict__ Y, int b0) {
  const int bid = blockIdx.x;           // nb*48: [bt][mq]
  const int mq = bid & 3;
  const int bt = bid >> 2;              // bl*12 + t
  const int bl = bt / 12, t = bt % 12;
  const int b = b0 + bl;
  const int tid = threadIdx.x;
  const int wv = tid >> 6, lane = tid & 63;
  const int l15 = lane & 15, l4 = lane >> 4;
  const int m0 = mq * 256 + wv * 64;

  const ushort_t* xg_b = (const ushort_t*)in;
  const float*    xg_f = (const float*)in;

  short8 bfr[4][2];
  #pragma unroll
  for (int mf = 0; mf < 4; ++mf) {
    const int m = m0 + mf * 16 + l15;
    #pragma unroll
    for (int ks = 0; ks < 2; ++ks) {
      #pragma unroll
      for (int j = 0; j < 8; ++j) {
        const int i = ks * 32 + l4 * 8 + j;
        const size_t adr = ((size_t)(b * C_ + i) * T_ + t) * N_ + m;
        ushort_t v = IN_BF16 ? xg_b[adr] : f2bf(xg_f[adr]);
        bfr[mf][ks][j] = (short)v;
      }
    }
  }

  const size_t rbase = (size_t)(bt * C_);
  #pragma unroll
  for (int k = 0; k < 3; ++k) {
    short8 afr[4][2];
    #pragma unroll
    for (int of = 0; of < 4; ++of)
      #pragma unroll
      for (int ks = 0; ks < 2; ++ks)
        afr[of][ks] = *(const short8*)&thA[(size_t)(k * 64 + of * 16 + l15) * 64 + ks * 32 + l4 * 8];

    f32x4 acc[4][4] = {};
    #pragma unroll
    for (int ks = 0; ks < 2; ++ks)
      #pragma unroll
      for (int of = 0; of < 4; ++of)
        #pragma unroll
        for (int mf = 0; mf < 4; ++mf)
          acc[of][mf] = __builtin_amdgcn_mfma_f32_16x16x32_bf16(afr[of][ks], bfr[mf][ks], acc[of][mf], 0, 0, 0);

    #pragma unroll
    for (int of = 0; of < 4; ++of)
      #pragma unroll
      for (int mf = 0; mf < 4; ++mf)
        #pragma unroll
        for (int r = 0; r < 4; ++r) {
          const int o = of * 16 + l4 * 4 + r;
          Y[(rbase + o) * KC_ + k * N_ + m0 + mf * 16 + l15] = f2bf(acc[of][mf][r]);
        }
  }
}

// ---------- 256x256-tile 8-phase GEMM (m201-faithful), C = Y @ Bt^T ----------
// LDS per buffer (65536 B): A [ks:2][row:256][64B] (32768) then B same (+32768).
// Swizzle (r4-proven): stored col-byte = logical ^ (((row>>3)&1)<<5); applied on
// global source (write side; gload_lds dest linear) and on ds_read address.
// 8 waves: wm2 = wid>>2 (M-half, 128 rows), wn4 = wid&3 (N base wn4*16, frags +64).
// Per K-tile u (buf p=u&1), 4 phases x {reads; 2 gloads; BAR; 16 MFMA; BAR}:
//   ph0: rd A ks0 mf0-3 + B ks0       ; stage A(u+1) ks1 h0,h1 -> buf p^1
//   ph1: rd A ks0 mf4-7               ; stage B(u+2) ks0 h0,h1 -> buf p
//   ph2: rd A ks1 mf0-3 + B ks1       ; stage A(u+2) ks0 h0,h1 -> buf p
//   ph3: rd A ks1 mf4-7               ; stage B(u+2) ks1 h0,h1 -> buf p ; vmcnt(6)
// Seal proof: each stage target's last reader drains (lgkmcnt pre-MFMA) before that
// phase's END barrier, which precedes the staging phase. vmcnt(6) at ph3(u) keeps
// exactly tile u+2's 6 units in flight and drains A(u+1)ks1 (issued ph0(u)) and all
// older -> tile u+1 fully landed before ph0(u+1). Tail: vmcnt(0) when u+2==NT.

#define STG_A(kt, s, h, dbuf) gload16(gA + (size_t)(h) * 128 * KC_ + (size_t)(kt) * 64 + (s) * 32, \
    (ushort_t*)(lp + (dbuf) + (s) * 16384 + (h) * 8192 + wofs))
#define STG_B(kt, s, h, dbuf) gload16(gB + (size_t)(h) * 128 * KC_ + (size_t)(kt) * 64 + (s) * 32, \
    (ushort_t*)(lp + (dbuf) + 32768 + (s) * 16384 + (h) * 8192 + wofs))

#define LD8(p) (*(const short8*)(p))

#define MFMA16P(g)                                                                \
  _Pragma("unroll") for (int i_ = 0; i_ < 4; ++i_)                                \
    _Pragma("unroll") for (int n_ = 0; n_ < 4; ++n_)                              \
      acc[(g) * 4 + i_][n_] =                                                     \
        __builtin_amdgcn_mfma_f32_16x16x32_bf16(af[i_], bfr[n_], acc[(g) * 4 + i_][n_], 0, 0, 0);

template<int RES_BF16>
__global__ __launch_bounds__(512, 1)
void gemm256(const ushort_t* __restrict__ Y, const ushort_t* __restrict__ Bt,
             const void* __restrict__ res, const float* __restrict__ bias,
             ushort_t* __restrict__ outb, int batch0) {
  // bijective XCD swizzle (m204); consecutive wg share mtile (4 ntiles)
  const int nwg = gridDim.x;
  int orig = blockIdx.x;
  int q8 = nwg >> 3, r8 = nwg & 7;
  int xcd = orig & 7, idx = orig >> 3;
  int wg = (xcd < r8 ? xcd * (q8 + 1) : r8 * (q8 + 1) + (xcd - r8) * q8) + idx;
  const int mtile = wg >> 2, ntile = wg & 3;

  const int tid = threadIdx.x;
  const int wid = tid >> 6, lane = tid & 63;
  const int wm2 = wid >> 2, wn4 = wid & 3;
  const int l15 = lane & 15, l4 = lane >> 4;

  __shared__ ushort_t LDSU[LB3];   // 131072 bytes (2 buffers)
  char* lp = (char*)LDSU;

  const int row0 = mtile * 256;
  const int n0 = ntile * 256;
  const int wofs = wid * 1024;

  // staging source base pointers (per-lane, swizzle pre-applied on global col)
  const int lam = lane >> 2, lc = lane & 3;
  const int colel = (lc * 8) ^ (((lam >> 3) & 1) << 4);
  const ushort_t* gA = Y  + (size_t)(row0 + wid * 16 + lam) * KC_ + colel;
  const ushort_t* gB = Bt + (size_t)(n0 + wid * 16 + lam) * KC_ + colel;

  // read-side lane byte bases (swizzle XOR on col)
  const int swz = ((l15 >> 3) & 1) << 5;
  const int a_base = wm2 * 8192 + l15 * 64 + ((l4 * 16) ^ swz);
  const int b_base = 32768 + wn4 * 1024 + l15 * 64 + ((l4 * 16) ^ swz);

  // prologue: tile0 all 8 units -> buf0; tile1 minus A-ks1 (6 units) -> buf1
  STG_A(0, 0, 0, 0); STG_A(0, 0, 1, 0); STG_A(0, 1, 0, 0); STG_A(0, 1, 1, 0);
  STG_B(0, 0, 0, 0); STG_B(0, 0, 1, 0); STG_B(0, 1, 0, 0); STG_B(0, 1, 1, 0);
  STG_B(1, 0, 0, LB3); STG_B(1, 0, 1, LB3);
  STG_A(1, 0, 0, LB3); STG_A(1, 0, 1, LB3);
  STG_B(1, 1, 0, LB3); STG_B(1, 1, 1, LB3);
  asm volatile("s_waitcnt vmcnt(6)" ::: "memory");   // tile0 landed
  __builtin_amdgcn_sched_barrier(0);
  __builtin_amdgcn_s_barrier();

  f32x4 acc[8][4] = {};
  short8 bfr[4];

  for (int u = 0; u < NT_; ++u) {
    const int bsel = (u & 1) ? LB3 : 0;
    const int nsel = bsel ^ LB3;
    const char* aks0 = lp + bsel + a_base;
    const char* bks0 = lp + bsel + b_base;

    { // ph0: A ks0 mf0-3 + B ks0; stage A(u+1) ks1
      short8 af[4];
      #pragma unroll
      for (int f = 0; f < 4; ++f) af[f] = LD8(aks0 + f * 1024);
      #pragma unroll
      for (int f = 0; f < 4; ++f) bfr[f] = LD8(bks0 + f * 4096);
      if (u + 1 < NT_) { STG_A(u + 1, 1, 0, nsel); STG_A(u + 1, 1, 1, nsel); }
      __builtin_amdgcn_s_barrier();
      __builtin_amdgcn_s_setprio(1);
      MFMA16P(0)
      __builtin_amdgcn_s_setprio(0);
      __builtin_amdgcn_s_barrier();
    }
    { // ph1: A ks0 mf4-7; stage B(u+2) ks0
      short8 af[4];
      #pragma unroll
      for (int f = 0; f < 4; ++f) af[f] = LD8(aks0 + (4 + f) * 1024);
      if (u + 2 < NT_) { STG_B(u + 2, 0, 0, bsel); STG_B(u + 2, 0, 1, bsel); }
      __builtin_amdgcn_s_barrier();
      __builtin_amdgcn_s_setprio(1);
      MFMA16P(1)
      __builtin_amdgcn_s_setprio(0);
      __builtin_amdgcn_s_barrier();
    }
    { // ph2: A ks1 mf0-3 + B ks1; stage A(u+2) ks0
      short8 af[4];
      #pragma unroll
      for (int f = 0; f < 4; ++f) af[f] = LD8(aks0 + 16384 + f * 1024);
      #pragma unroll
      for (int f = 0; f < 4; ++f) bfr[f] = LD8(bks0 + 16384 + f * 4096);
      if (u + 2 < NT_) { STG_A(u + 2, 0, 0, bsel); STG_A(u + 2, 0, 1, bsel); }
      __builtin_amdgcn_s_barrier();
      __builtin_amdgcn_s_setprio(1);
      MFMA16P(0)
      __builtin_amdgcn_s_setprio(0);
      __builtin_amdgcn_s_barrier();
    }
    { // ph3: A ks1 mf4-7; stage B(u+2) ks1; counted vmcnt
      short8 af[4];
      #pragma unroll
      for (int f = 0; f < 4; ++f) af[f] = LD8(aks0 + 16384 + (4 + f) * 1024);
      if (u + 2 < NT_) {
        STG_B(u + 2, 1, 0, bsel); STG_B(u + 2, 1, 1, bsel);
        asm volatile("s_waitcnt vmcnt(6)" ::: "memory");  // tile u+1 complete
      } else {
        asm volatile("s_waitcnt vmcnt(0)" ::: "memory");  // tail drain
      }
      __builtin_amdgcn_sched_barrier(0);
      __builtin_amdgcn_s_barrier();
      __builtin_amdgcn_s_setprio(1);
      MFMA16P(1)
      __builtin_amdgcn_s_setprio(0);
      __builtin_amdgcn_s_barrier();
    }
  }

  // epilogue: bias + residual + relu, bf16 store
  const float*    resf = (const float*)res;
  const ushort_t* resb = (const ushort_t*)res;
  const int gb = batch0 + mtile / 3;
  const int rowb0 = (mtile % 3) * 256 + wm2 * 128;
  const int colb = n0 + wn4 * 16 + l15;
  #pragma unroll
  for (int mf = 0; mf < 8; ++mf) {
    #pragma unroll
    for (int r = 0; r < 4; ++r) {
      int rowb = rowb0 + mf * 16 + l4 * 4 + r;
      int t = rowb >> 6, o = rowb & 63;
      float bs = bias[o];
      size_t base = ((size_t)(gb * C_ + o) * T_ + t) * N_;
      #pragma unroll
      for (int nf = 0; nf < 4; ++nf) {
        int col = colb + nf * 64;
        float rv = RES_BF16 ? bf2f(resb[base + col]) : resf[base + col];
        float v = acc[mf][nf][r] + bs + rv;
        v = fmaxf(v, 0.0f);
        outb[base + col] = f2bf(v);
      }
    }
  }
}

// ---------- FC: out[b,t,n,o2] = sum_o fw[o2,o]*x2[b,o,t,n] + fb[o2] ----------
__global__ __launch_bounds__(256, 2)
void fc_kernel(const ushort_t* __restrict__ x2, const float* __restrict__ fw,
               const float* __restrict__ fb, float* __restrict__ out) {
  int bid = blockIdx.x;
  int nt = bid & 15, btid = bid >> 4;
  int t = btid % 12, b = btid / 12;
  int n0 = nt << 6;
  int tid = threadIdx.x;
  __shared__ float xt[64 * 64];
  __shared__ float wl[64 * 64];
  #pragma unroll
  for (int j = 0; j < 2; ++j) {
    int c = tid + j * 256;
    int row = c >> 3, col = (c & 7) << 3;
    short8 v = *(const short8*)&x2[((b * C_ + row) * T_ + t) * N_ + n0 + col];
    #pragma unroll
    for (int q = 0; q < 8; ++q) xt[row * 64 + col + q] = bf2f((ushort_t)v[q]);
  }
  #pragma unroll
  for (int j = 0; j < 4; ++j) {
    int c = tid + j * 256;
    int o2 = c >> 4, o4 = (c & 15) << 2;
    float4 v = *(const float4*)&fw[o2 * 64 + o4];
    wl[(o4 + 0) * 64 + o2] = v.x; wl[(o4 + 1) * 64 + o2] = v.y;
    wl[(o4 + 2) * 64 + o2] = v.z; wl[(o4 + 3) * 64 + o2] = v.w;
  }
  __syncthreads();
  int p = tid & 31, ng = tid >> 5;
  float a0[8] = {}, a1[8] = {};
  for (int o = 0; o < 64; ++o) {
    float w0 = wl[o * 64 + p], w1 = wl[o * 64 + p + 32];
    float4 xa = *(const float4*)&xt[o * 64 + ng * 8];
    float4 xb = *(const float4*)&xt[o * 64 + ng * 8 + 4];
    float xv[8] = {xa.x, xa.y, xa.z, xa.w, xb.x, xb.y, xb.z, xb.w};
    #pragma unroll
    for (int j = 0; j < 8; ++j) { a0[j] = fmaf(w0, xv[j], a0[j]); a1[j] = fmaf(w1, xv[j], a1[j]); }
  }
  float fb0 = fb[p], fb1 = fb[p + 32];
  int obase = (b * T_ + t) * N_ + n0 + ng * 8;
  #pragma unroll
  for (int j = 0; j < 8; ++j) {
    out[(obase + j) * 64 + p]      = a0[j] + fb0;
    out[(obase + j) * 64 + p + 32] = a1[j] + fb1;
  }
}

extern "C" void kernel_launch(void* const* d_in, const int* in_sizes, int n_in,
                              void* d_out, int out_size, void* d_ws, size_t ws_size,
                              hipStream_t stream) {
  const float* x   = (const float*)d_in[0];
  const float* Lk  = (const float*)d_in[1];
  const float* th1 = (const float*)d_in[2];
  const float* b1  = (const float*)d_in[3];
  const float* th2 = (const float*)d_in[4];
  const float* b2  = (const float*)d_in[5];
  const float* fcw = (const float*)d_in[6];
  const float* fcb = (const float*)d_in[7];

  char* ws = (char*)d_ws;
  size_t off = 0;
  auto alloc = [&](size_t bytes) { size_t p = off; off += (bytes + 255) & ~(size_t)255; return p; };
  size_t oBt = alloc((size_t)KC_ * N_ * 2);
  size_t oTh = alloc((size_t)2 * 3 * 64 * 64 * 2);
  size_t oX2 = alloc((size_t)B_ * C_ * T_ * N_ * 2);
  size_t perB = (size_t)RPB * KC_ * 2;
  size_t avail = ws_size > off ? ws_size - off : 0;
  int NB = (int)(avail / perB);
  if (NB > B_) NB = B_;
  if (NB < 1) NB = 1;

  ushort_t* Bt = (ushort_t*)(ws + oBt);
  ushort_t* Th = (ushort_t*)(ws + oTh);
  ushort_t* X2 = (ushort_t*)(ws + oX2);
  ushort_t* Yb = (ushort_t*)(ws + off);
  ushort_t* X1 = (ushort_t*)d_out;

  prep_th<<<96, 256, 0, stream>>>(th1, th2, Th);
  prep_bt<<<1536, 256, 0, stream>>>(Lk, Bt);

  for (int b0 = 0; b0 < B_; b0 += NB) {
    int nb = (b0 + NB <= B_) ? NB : (B_ - b0);
    mix_mfma<0><<<nb * 48, 256, 0, stream>>>((const void*)x, Th, Yb, b0);
    gemm256<0><<<dim3(12 * nb), 512, 0, stream>>>(Yb, Bt, (const void*)x, b1, X1, b0);
  }
  for (int b0 = 0; b0 < B_; b0 += NB) {
    int nb = (b0 + NB <= B_) ? NB : (B_ - b0);
    mix_mfma<1><<<nb * 48, 256, 0, stream>>>((const void*)X1, Th + 12288, Yb, b0);
    gemm256<1><<<dim3(12 * nb), 512, 0, stream>>>(Yb, Bt, (const void*)X1, b2, X2, b0);
  }
  fc_kernel<<<32 * 12 * 16, 256, 0, stream>>>(X2, fcw, fcb, (float*)d_out);
}

// Round 12
// 480.775 us; speedup vs baseline: 1.1747x; 1.1571x over previous
//
#include <hip/hip_runtime.h>

typedef unsigned short ushort_t;
typedef unsigned long long u64;
typedef short short8 __attribute__((ext_vector_type(8)));
typedef float f32x4 __attribute__((ext_vector_type(4)));

#define B_   32
#define C_   64
#define T_   12
#define N_   1024
#define KS_  3
#define KC_  3072
#define RPB  768
#define NT_  48          // K-tiles of 64
#define BM_  192
#define LBUF 57344       // bytes per LDS buffer: A 192*64*2 (=24576) + B 256*64*2 (=32768)
#define ABYT 24576       // A region bytes
#define BPLN 16384       // B plane stride

__device__ __forceinline__ float bf2f(ushort_t u) {
  union { unsigned u; float f; } v; v.u = ((unsigned)u) << 16; return v.f;
}
__device__ __forceinline__ ushort_t f2bf(float f) {
  union { float f; unsigned u; } v; v.f = f;
  unsigned r = v.u + 0x7FFFu + ((v.u >> 16) & 1u);
  return (ushort_t)(r >> 16);
}

__device__ __forceinline__ void gload16(const ushort_t* g, ushort_t* l) {
  __builtin_amdgcn_global_load_lds(
      (const __attribute__((address_space(1))) unsigned int*)g,
      (__attribute__((address_space(3))) unsigned int*)l, 16, 0, 0);
}

// ---------- prep: thA[l][k][o][i] = bf16(theta_l[i][o][k]) ----------
__global__ void prep_th(const float* __restrict__ th1, const float* __restrict__ th2,
                        ushort_t* __restrict__ out) {
  int id = blockIdx.x * 256 + threadIdx.x;          // 2*3*64*64 = 24576
  if (id >= 24576) return;
  int l = id / 12288, rem = id % 12288;
  int k = rem / 4096;
  int o = (rem >> 6) & 63;
  int i = rem & 63;
  const float* th = l ? th2 : th1;
  out[id] = f2bf(th[(i * 64 + o) * 3 + k]);
}

// ---------- prep: Bt[n][k*1024+m] = bf16(Lk[k][n][m]) ----------
__global__ void prep_bt(const float* __restrict__ Lk, ushort_t* __restrict__ Bt) {
  int id = blockIdx.x * 256 + threadIdx.x;
  int k = id >> 17, rem = id & 131071;
  int n = rem >> 7, mc = rem & 127;
  int m = mc << 3;
  const float* src = Lk + ((k * N_ + n) * N_ + m);
  float4 v0 = *(const float4*)src;
  float4 v1 = *(const float4*)(src + 4);
  short8 o8;
  o8[0] = (short)f2bf(v0.x); o8[1] = (short)f2bf(v0.y);
  o8[2] = (short)f2bf(v0.z); o8[3] = (short)f2bf(v0.w);
  o8[4] = (short)f2bf(v1.x); o8[5] = (short)f2bf(v1.y);
  o8[6] = (short)f2bf(v1.z); o8[7] = (short)f2bf(v1.w);
  *(short8*)&Bt[n * KC_ + k * N_ + m] = o8;
}

// ---------- MFMA channel mix ----------
template<int IN_BF16>
__global__ __launch_bounds__(256, 2)
void mix_mfma(const void* __restrict__ in, const ushort_t* __restrict__ thA,
              ushort_t* __restrict__ Y, int b0) {
  const int bid = blockIdx.x;           // nb*48: [bt][mq]
  const int mq = bid & 3;
  const int bt = bid >> 2;              // bl*12 + t
  const int bl = bt / 12, t = bt % 12;
  const int b = b0 + bl;
  const int tid = threadIdx.x;
  const int wv = tid >> 6, lane = tid & 63;
  const int l15 = lane & 15, l4 = lane >> 4;
  const int m0 = mq * 256 + wv * 64;

  const ushort_t* xg_b = (const ushort_t*)in;
  const float*    xg_f = (const float*)in;

  short8 bfr[4][2];
  #pragma unroll
  for (int mf = 0; mf < 4; ++mf) {
    const int m = m0 + mf * 16 + l15;
    #pragma unroll
    for (int ks = 0; ks < 2; ++ks) {
      #pragma unroll
      for (int j = 0; j < 8; ++j) {
        const int i = ks * 32 + l4 * 8 + j;
        const size_t adr = ((size_t)(b * C_ + i) * T_ + t) * N_ + m;
        ushort_t v = IN_BF16 ? xg_b[adr] : f2bf(xg_f[adr]);
        bfr[mf][ks][j] = (short)v;
      }
    }
  }

  const size_t rbase = (size_t)(bt * C_);
  #pragma unroll
  for (int k = 0; k < 3; ++k) {
    short8 afr[4][2];
    #pragma unroll
    for (int of = 0; of < 4; ++of)
      #pragma unroll
      for (int ks = 0; ks < 2; ++ks)
        afr[of][ks] = *(const short8*)&thA[(size_t)(k * 64 + of * 16 + l15) * 64 + ks * 32 + l4 * 8];

    f32x4 acc[4][4] = {};
    #pragma unroll
    for (int ks = 0; ks < 2; ++ks)
      #pragma unroll
      for (int of = 0; of < 4; ++of)
        #pragma unroll
        for (int mf = 0; mf < 4; ++mf)
          acc[of][mf] = __builtin_amdgcn_mfma_f32_16x16x32_bf16(afr[of][ks], bfr[mf][ks], acc[of][mf], 0, 0, 0);

    #pragma unroll
    for (int of = 0; of < 4; ++of)
      #pragma unroll
      for (int mf = 0; mf < 4; ++mf)
        #pragma unroll
        for (int r = 0; r < 4; ++r) {
          const int o = of * 16 + l4 * 4 + r;
          Y[(rbase + o) * KC_ + k * N_ + m0 + mf * 16 + l15] = f2bf(acc[of][mf][r]);
        }
  }
}

// ---------- 192x256-tile phased GEMM with depth-1 fragment read-ahead (r6, best) ----------

#define MFMA12G(g, A, Bv)                                                                       \
  acc[3*(g)+0][0] = __builtin_amdgcn_mfma_f32_16x16x32_bf16(A[0], Bv[0], acc[3*(g)+0][0],0,0,0); \
  acc[3*(g)+0][1] = __builtin_amdgcn_mfma_f32_16x16x32_bf16(A[0], Bv[1], acc[3*(g)+0][1],0,0,0); \
  acc[3*(g)+0][2] = __builtin_amdgcn_mfma_f32_16x16x32_bf16(A[0], Bv[2], acc[3*(g)+0][2],0,0,0); \
  acc[3*(g)+0][3] = __builtin_amdgcn_mfma_f32_16x16x32_bf16(A[0], Bv[3], acc[3*(g)+0][3],0,0,0); \
  acc[3*(g)+1][0] = __builtin_amdgcn_mfma_f32_16x16x32_bf16(A[1], Bv[0], acc[3*(g)+1][0],0,0,0); \
  acc[3*(g)+1][1] = __builtin_amdgcn_mfma_f32_16x16x32_bf16(A[1], Bv[1], acc[3*(g)+1][1],0,0,0); \
  acc[3*(g)+1][2] = __builtin_amdgcn_mfma_f32_16x16x32_bf16(A[1], Bv[2], acc[3*(g)+1][2],0,0,0); \
  acc[3*(g)+1][3] = __builtin_amdgcn_mfma_f32_16x16x32_bf16(A[1], Bv[3], acc[3*(g)+1][3],0,0,0); \
  acc[3*(g)+2][0] = __builtin_amdgcn_mfma_f32_16x16x32_bf16(A[2], Bv[0], acc[3*(g)+2][0],0,0,0); \
  acc[3*(g)+2][1] = __builtin_amdgcn_mfma_f32_16x16x32_bf16(A[2], Bv[1], acc[3*(g)+2][1],0,0,0); \
  acc[3*(g)+2][2] = __builtin_amdgcn_mfma_f32_16x16x32_bf16(A[2], Bv[2], acc[3*(g)+2][2],0,0,0); \
  acc[3*(g)+2][3] = __builtin_amdgcn_mfma_f32_16x16x32_bf16(A[2], Bv[3], acc[3*(g)+2][3],0,0,0);

#define STAGE_A(kt, j) gload16(gA##j + (size_t)(kt) * 64,                                   \
    (ushort_t*)(lp + (((kt) & 1) ? LBUF : 0) + (j) * 8192 + wofs))
#define STAGE_B(kt, j) gload16(gB##j + (size_t)(kt) * 64,                                   \
    (ushort_t*)(lp + (((kt) & 1) ? LBUF : 0) + ABYT + (j) * 8192 + wofs))

#define LD8(p) (*(const short8*)(p))

template<int RES_BF16>
__global__ __launch_bounds__(512, 2)
void gemm8p(const ushort_t* __restrict__ Y, const ushort_t* __restrict__ Bt,
            const void* __restrict__ res, const float* __restrict__ bias,
            ushort_t* __restrict__ outb, int batch0) {
  const int nwg = gridDim.x;
  int orig = blockIdx.x;
  int q8 = nwg >> 3;
  int wg = (orig & 7) * q8 + (orig >> 3);
  const int mtile = wg >> 2, ntile = wg & 3;

  const int tid = threadIdx.x;
  const int wid = tid >> 6, lane = tid & 63;
  const int wm = wid >> 2, wn = wid & 3;
  const int l15 = lane & 15, l4 = lane >> 4;

  __shared__ ushort_t LDSU[LBUF];   // 114688 bytes total (2 buffers)
  char* lp = (char*)LDSU;

  const int row0 = mtile * BM_;
  const int n0 = ntile * 256;
  const int wofs = wid * 1024;

  const int lam = lane >> 2, lc = lane & 3;
  const ushort_t *gA0, *gA1, *gA2, *gB0, *gB1, *gB2, *gB3;
  {
    int p, s, row, colel;
    p = 0 * 128 + wid * 16 + lam; s = p >= 192 ? 1 : 0; row = p - s * 192;
    colel = (lc * 8) ^ (((row >> 3) & 1) << 4);
    gA0 = Y + (size_t)(row0 + row) * KC_ + s * 32 + colel;
    p = 1 * 128 + wid * 16 + lam; s = p >= 192 ? 1 : 0; row = p - s * 192;
    colel = (lc * 8) ^ (((row >> 3) & 1) << 4);
    gA1 = Y + (size_t)(row0 + row) * KC_ + s * 32 + colel;
    p = 2 * 128 + wid * 16 + lam; s = p >= 192 ? 1 : 0; row = p - s * 192;
    colel = (lc * 8) ^ (((row >> 3) & 1) << 4);
    gA2 = Y + (size_t)(row0 + row) * KC_ + s * 32 + colel;
    p = 0 * 128 + wid * 16 + lam; s = p >> 8; row = p & 255;
    colel = (lc * 8) ^ (((row >> 3) & 1) << 4);
    gB0 = Bt + (size_t)(n0 + row) * KC_ + s * 32 + colel;
    p = 1 * 128 + wid * 16 + lam; s = p >> 8; row = p & 255;
    colel = (lc * 8) ^ (((row >> 3) & 1) << 4);
    gB1 = Bt + (size_t)(n0 + row) * KC_ + s * 32 + colel;
    p = 2 * 128 + wid * 16 + lam; s = p >> 8; row = p & 255;
    colel = (lc * 8) ^ (((row >> 3) & 1) << 4);
    gB2 = Bt + (size_t)(n0 + row) * KC_ + s * 32 + colel;
    p = 3 * 128 + wid * 16 + lam; s = p >> 8; row = p & 255;
    colel = (lc * 8) ^ (((row >> 3) & 1) << 4);
    gB3 = Bt + (size_t)(n0 + row) * KC_ + s * 32 + colel;
  }

  const int swz = ((l15 >> 3) & 1) << 5;
  const int a_base = (wm * 16 + l15) * 64 + ((l4 * 16) ^ swz);
  const int b_base = ABYT + (wn * 16 + l15) * 64 + ((l4 * 16) ^ swz);

  // prologue: tile0 fully, tile1 minus A2 (13 units); vmcnt(6) -> tile0 landed
  STAGE_B(0, 0); STAGE_B(0, 1); STAGE_B(0, 2); STAGE_B(0, 3);
  STAGE_A(0, 0); STAGE_A(0, 1); STAGE_A(0, 2);
  STAGE_B(1, 0); STAGE_B(1, 1); STAGE_B(1, 2); STAGE_B(1, 3);
  STAGE_A(1, 0); STAGE_A(1, 1);
  asm volatile("s_waitcnt vmcnt(6)" ::: "memory");
  __builtin_amdgcn_s_barrier();
  __builtin_amdgcn_sched_barrier(0);

  f32x4 acc[6][4] = {};
  short8 aA[3], aB[3], bS0[4], bS1[4];

  { // pre-read G0(0): A s0 m0-2 + B s0
    const char* abp = lp + a_base;
    const char* bbp = lp + b_base;
    aA[0] = LD8(abp);          aA[1] = LD8(abp + 2048);   aA[2] = LD8(abp + 4096);
    bS0[0] = LD8(bbp);         bS0[1] = LD8(bbp + 4096);
    bS0[2] = LD8(bbp + 8192);  bS0[3] = LD8(bbp + 12288);
  }

  for (int u = 0; u < NT_; ++u) {
    const char* abp = lp + ((u & 1) ? LBUF : 0) + a_base;
    const char* bbp = lp + ((u & 1) ? LBUF : 0) + b_base;
    const char* abn = lp + ((u & 1) ? 0 : LBUF) + a_base;
    const char* bbn = lp + ((u & 1) ? 0 : LBUF) + b_base;

    { // phase 0: MFMA(G0) ; read G1 ; stage A2(u+1)
      if (u + 1 < NT_) STAGE_A(u + 1, 2);
      __builtin_amdgcn_s_barrier();
      __builtin_amdgcn_sched_barrier(0);
      aB[0] = LD8(abp + 6144); aB[1] = LD8(abp + 8192); aB[2] = LD8(abp + 10240);
      __builtin_amdgcn_sched_barrier(0);
      __builtin_amdgcn_s_setprio(1);
      MFMA12G(0, aA, bS0)
      __builtin_amdgcn_s_setprio(0);
      __builtin_amdgcn_s_barrier();
    }
    { // phase 1: MFMA(G1) ; read G2 ; stage B0,B1(u+2)
      if (u + 2 < NT_) { STAGE_B(u + 2, 0); STAGE_B(u + 2, 1); }
      __builtin_amdgcn_s_barrier();
      __builtin_amdgcn_sched_barrier(0);
      aA[0] = LD8(abp + 12288);         aA[1] = LD8(abp + 12288 + 2048);
      aA[2] = LD8(abp + 12288 + 4096);
      bS1[0] = LD8(bbp + BPLN);         bS1[1] = LD8(bbp + BPLN + 4096);
      bS1[2] = LD8(bbp + BPLN + 8192);  bS1[3] = LD8(bbp + BPLN + 12288);
      __builtin_amdgcn_sched_barrier(0);
      __builtin_amdgcn_s_setprio(1);
      MFMA12G(1, aB, bS0)
      __builtin_amdgcn_s_setprio(0);
      __builtin_amdgcn_s_barrier();
    }
    { // phase 2: MFMA(G2) ; read G3
      __builtin_amdgcn_s_barrier();
      __builtin_amdgcn_sched_barrier(0);
      aB[0] = LD8(abp + 12288 + 6144);
      aB[1] = LD8(abp + 12288 + 8192);
      aB[2] = LD8(abp + 12288 + 10240);
      __builtin_amdgcn_sched_barrier(0);
      __builtin_amdgcn_s_setprio(1);
      MFMA12G(0, aA, bS1)
      __builtin_amdgcn_s_setprio(0);
      __builtin_amdgcn_s_barrier();
    }
    { // phase 3: MFMA(G3) ; stage B2,B3,A0,A1(u+2) ; vmcnt ; read G0(u+1)
      if (u + 2 < NT_) {
        STAGE_B(u + 2, 2); STAGE_B(u + 2, 3);
        STAGE_A(u + 2, 0); STAGE_A(u + 2, 1);
        asm volatile("s_waitcnt vmcnt(6)" ::: "memory");
      } else if (u + 2 == NT_) {
        asm volatile("s_waitcnt vmcnt(0)" ::: "memory");
      }
      __builtin_amdgcn_s_barrier();
      __builtin_amdgcn_sched_barrier(0);
      if (u + 1 < NT_) {
        aA[0] = LD8(abn);          aA[1] = LD8(abn + 2048);   aA[2] = LD8(abn + 4096);
        bS0[0] = LD8(bbn);         bS0[1] = LD8(bbn + 4096);
        bS0[2] = LD8(bbn + 8192);  bS0[3] = LD8(bbn + 12288);
      }
      __builtin_amdgcn_sched_barrier(0);
      __builtin_amdgcn_s_setprio(1);
      MFMA12G(1, aB, bS1)
      __builtin_amdgcn_s_setprio(0);
      __builtin_amdgcn_s_barrier();
    }
  }

  // epilogue: bias + residual + relu, bf16 store
  const float*    resf = (const float*)res;
  const ushort_t* resb = (const ushort_t*)res;
  const int gb = batch0 + (mtile >> 2);
  const int rowb0 = (mtile & 3) * BM_;
  const int colb = n0 + wn * 16 + l15;
  #pragma unroll
  for (int mf = 0; mf < 6; ++mf) {
    #pragma unroll
    for (int r = 0; r < 4; ++r) {
      int rl = mf * 32 + wm * 16 + l4 * 4 + r;
      int rowb = rowb0 + rl;
      int t = rowb >> 6, o = rowb & 63;
      float bs = bias[o];
      size_t base = ((size_t)(gb * C_ + o) * T_ + t) * N_;
      #pragma unroll
      for (int nf = 0; nf < 4; ++nf) {
        int col = colb + nf * 64;
        float rv = RES_BF16 ? bf2f(resb[base + col]) : resf[base + col];
        float v = acc[mf][nf][r] + bs + rv;
        v = fmaxf(v, 0.0f);
        outb[base + col] = f2bf(v);
      }
    }
  }
}

// ---------- FC via MFMA: out[btn, o2] = sum_o X2[b,o,t,n] * fw[o2,o] + fb[o2] ----------
// Per wave: 64 btn-rows x 64 o2 x K=64 -> 32 MFMA. A-frags gathered per-lane from X2
// (16-lane groups read consecutive n -> 32B segments, L2/L3-resident); W-frags from fw
// (16KB, L2-hot). Conventions identical to mix_mfma (verified): A-side rows at l15,
// k at l4*8+j; D row = group + l4*4 + r, col = group + l15.
__global__ __launch_bounds__(256, 2)
void fc_mfma(const ushort_t* __restrict__ x2, const float* __restrict__ fw,
             const float* __restrict__ fb, float* __restrict__ out) {
  const int tid = threadIdx.x;
  const int wv = tid >> 6, lane = tid & 63;
  const int l15 = lane & 15, l4 = lane >> 4;
  const int row0 = blockIdx.x * 256 + wv * 64;   // btn base for this wave

  // W-frags: wfr[nf][ks], lane holds fw[o2 = nf*16+l15][o = ks*32 + l4*8 + j]
  short8 wfr[4][2];
  #pragma unroll
  for (int nf = 0; nf < 4; ++nf) {
    const float* wsrc = fw + (nf * 16 + l15) * 64;
    #pragma unroll
    for (int ks = 0; ks < 2; ++ks) {
      float4 wa = *(const float4*)(wsrc + ks * 32 + l4 * 8);
      float4 wb = *(const float4*)(wsrc + ks * 32 + l4 * 8 + 4);
      short8 w8;
      w8[0] = (short)f2bf(wa.x); w8[1] = (short)f2bf(wa.y);
      w8[2] = (short)f2bf(wa.z); w8[3] = (short)f2bf(wa.w);
      w8[4] = (short)f2bf(wb.x); w8[5] = (short)f2bf(wb.y);
      w8[6] = (short)f2bf(wb.z); w8[7] = (short)f2bf(wb.w);
      wfr[nf][ks] = w8;
    }
  }

  f32x4 acc[4][4] = {};
  #pragma unroll
  for (int mf = 0; mf < 4; ++mf) {
    const int row = row0 + mf * 16 + l15;        // btn = b*12288 + t*1024 + n
    const int n = row & 1023, tb = row >> 10;
    const int b = tb / 12, t = tb - b * 12;
    const size_t base = ((size_t)(b * 768) + t) * 1024 + n;   // + o*12288
    #pragma unroll
    for (int ks = 0; ks < 2; ++ks) {
      short8 af;
      #pragma unroll
      for (int j = 0; j < 8; ++j) {
        const int o = ks * 32 + l4 * 8 + j;
        af[j] = (short)x2[base + (size_t)o * 12288];
      }
      #pragma unroll
      for (int nf = 0; nf < 4; ++nf)
        acc[mf][nf] = __builtin_amdgcn_mfma_f32_16x16x32_bf16(af, wfr[nf][ks], acc[mf][nf], 0, 0, 0);
    }
  }

  #pragma unroll
  for (int mf = 0; mf < 4; ++mf)
    #pragma unroll
    for (int nf = 0; nf < 4; ++nf) {
      const float fbv = fb[nf * 16 + l15];
      #pragma unroll
      for (int r = 0; r < 4; ++r)
        out[(size_t)(row0 + mf * 16 + l4 * 4 + r) * 64 + nf * 16 + l15] = acc[mf][nf][r] + fbv;
    }
}

extern "C" void kernel_launch(void* const* d_in, const int* in_sizes, int n_in,
                              void* d_out, int out_size, void* d_ws, size_t ws_size,
                              hipStream_t stream) {
  const float* x   = (const float*)d_in[0];
  const float* Lk  = (const float*)d_in[1];
  const float* th1 = (const float*)d_in[2];
  const float* b1  = (const float*)d_in[3];
  const float* th2 = (const float*)d_in[4];
  const float* b2  = (const float*)d_in[5];
  const float* fcw = (const float*)d_in[6];
  const float* fcb = (const float*)d_in[7];

  char* ws = (char*)d_ws;
  size_t off = 0;
  auto alloc = [&](size_t bytes) { size_t p = off; off += (bytes + 255) & ~(size_t)255; return p; };
  size_t oBt = alloc((size_t)KC_ * N_ * 2);
  size_t oTh = alloc((size_t)2 * 3 * 64 * 64 * 2);
  size_t oX2 = alloc((size_t)B_ * C_ * T_ * N_ * 2);
  size_t perB = (size_t)RPB * KC_ * 2;
  size_t avail = ws_size > off ? ws_size - off : 0;
  int NB = (int)(avail / perB);
  if (NB > B_) NB = B_;
  if (NB < 1) NB = 1;

  ushort_t* Bt = (ushort_t*)(ws + oBt);
  ushort_t* Th = (ushort_t*)(ws + oTh);
  ushort_t* X2 = (ushort_t*)(ws + oX2);
  ushort_t* Yb = (ushort_t*)(ws + off);
  ushort_t* X1 = (ushort_t*)d_out;

  prep_th<<<96, 256, 0, stream>>>(th1, th2, Th);
  prep_bt<<<1536, 256, 0, stream>>>(Lk, Bt);

  for (int b0 = 0; b0 < B_; b0 += NB) {
    int nb = (b0 + NB <= B_) ? NB : (B_ - b0);
    mix_mfma<0><<<nb * 48, 256, 0, stream>>>((const void*)x, Th, Yb, b0);
    gemm8p<0><<<dim3(16 * nb), 512, 0, stream>>>(Yb, Bt, (const void*)x, b1, X1, b0);
  }
  for (int b0 = 0; b0 < B_; b0 += NB) {
    int nb = (b0 + NB <= B_) ? NB : (B_ - b0);
    mix_mfma<1><<<nb * 48, 256, 0, stream>>>((const void*)X1, Th + 12288, Yb, b0);
    gemm8p<1><<<dim3(16 * nb), 512, 0, stream>>>(Yb, Bt, (const void*)X1, b2, X2, b0);
  }
  fc_mfma<<<1536, 256, 0, stream>>>(X2, fcw, fcb, (float*)d_out);
}

// Round 14
// 444.370 us; speedup vs baseline: 1.2709x; 1.0819x over previous
//
#include <hip/hip_runtime.h>

typedef unsigned short ushort_t;
typedef unsigned long long u64;
typedef short short8 __attribute__((ext_vector_type(8)));
typedef float f32x4 __attribute__((ext_vector_type(4)));

#define B_   32
#define C_   64
#define T_   12
#define N_   1024
#define KS_  3
#define KC_  3072
#define RPB  768
#define NT_  48          // K-tiles of 64
#define BM_  192
#define LBUF 57344       // bytes per LDS buffer: A 192*64*2 (=24576) + B 256*64*2 (=32768)
#define ABYT 24576       // A region bytes
#define BPLN 16384       // B plane stride

__device__ __forceinline__ float bf2f(ushort_t u) {
  union { unsigned u; float f; } v; v.u = ((unsigned)u) << 16; return v.f;
}
__device__ __forceinline__ ushort_t f2bf(float f) {
  union { float f; unsigned u; } v; v.f = f;
  unsigned r = v.u + 0x7FFFu + ((v.u >> 16) & 1u);
  return (ushort_t)(r >> 16);
}

__device__ __forceinline__ void gload16(const ushort_t* g, ushort_t* l) {
  __builtin_amdgcn_global_load_lds(
      (const __attribute__((address_space(1))) unsigned int*)g,
      (__attribute__((address_space(3))) unsigned int*)l, 16, 0, 0);
}

// ---------- prep: thA[l][k][o][i] = bf16(theta_l[i][o][k]) ----------
__global__ void prep_th(const float* __restrict__ th1, const float* __restrict__ th2,
                        ushort_t* __restrict__ out) {
  int id = blockIdx.x * 256 + threadIdx.x;          // 2*3*64*64 = 24576
  if (id >= 24576) return;
  int l = id / 12288, rem = id % 12288;
  int k = rem / 4096;
  int o = (rem >> 6) & 63;
  int i = rem & 63;
  const float* th = l ? th2 : th1;
  out[id] = f2bf(th[(i * 64 + o) * 3 + k]);
}

// ---------- prep: Bt[n][k*1024+m] = bf16(Lk[k][n][m]) ----------
__global__ void prep_bt(const float* __restrict__ Lk, ushort_t* __restrict__ Bt) {
  int id = blockIdx.x * 256 + threadIdx.x;
  int k = id >> 17, rem = id & 131071;
  int n = rem >> 7, mc = rem & 127;
  int m = mc << 3;
  const float* src = Lk + ((k * N_ + n) * N_ + m);
  float4 v0 = *(const float4*)src;
  float4 v1 = *(const float4*)(src + 4);
  short8 o8;
  o8[0] = (short)f2bf(v0.x); o8[1] = (short)f2bf(v0.y);
  o8[2] = (short)f2bf(v0.z); o8[3] = (short)f2bf(v0.w);
  o8[4] = (short)f2bf(v1.x); o8[5] = (short)f2bf(v1.y);
  o8[6] = (short)f2bf(v1.z); o8[7] = (short)f2bf(v1.w);
  *(short8*)&Bt[n * KC_ + k * N_ + m] = o8;
}

// ---------- MFMA channel mix (layer 1 only: fp32 input) ----------
__global__ __launch_bounds__(256, 2)
void mix_mfma(const float* __restrict__ xg_f, const ushort_t* __restrict__ thA,
              ushort_t* __restrict__ Y, int b0) {
  const int bid = blockIdx.x;           // nb*48: [bt][mq]
  const int mq = bid & 3;
  const int bt = bid >> 2;              // bl*12 + t
  const int bl = bt / 12, t = bt % 12;
  const int b = b0 + bl;
  const int tid = threadIdx.x;
  const int wv = tid >> 6, lane = tid & 63;
  const int l15 = lane & 15, l4 = lane >> 4;
  const int m0 = mq * 256 + wv * 64;

  short8 bfr[4][2];
  #pragma unroll
  for (int mf = 0; mf < 4; ++mf) {
    const int m = m0 + mf * 16 + l15;
    #pragma unroll
    for (int ks = 0; ks < 2; ++ks) {
      #pragma unroll
      for (int j = 0; j < 8; ++j) {
        const int i = ks * 32 + l4 * 8 + j;
        const size_t adr = ((size_t)(b * C_ + i) * T_ + t) * N_ + m;
        bfr[mf][ks][j] = (short)f2bf(xg_f[adr]);
      }
    }
  }

  const size_t rbase = (size_t)(bt * C_);
  #pragma unroll
  for (int k = 0; k < 3; ++k) {
    short8 afr[4][2];
    #pragma unroll
    for (int of = 0; of < 4; ++of)
      #pragma unroll
      for (int ks = 0; ks < 2; ++ks)
        afr[of][ks] = *(const short8*)&thA[(size_t)(k * 64 + of * 16 + l15) * 64 + ks * 32 + l4 * 8];

    f32x4 acc[4][4] = {};
    #pragma unroll
    for (int ks = 0; ks < 2; ++ks)
      #pragma unroll
      for (int of = 0; of < 4; ++of)
        #pragma unroll
        for (int mf = 0; mf < 4; ++mf)
          acc[of][mf] = __builtin_amdgcn_mfma_f32_16x16x32_bf16(afr[of][ks], bfr[mf][ks], acc[of][mf], 0, 0, 0);

    #pragma unroll
    for (int of = 0; of < 4; ++of)
      #pragma unroll
      for (int mf = 0; mf < 4; ++mf)
        #pragma unroll
        for (int r = 0; r < 4; ++r) {
          const int o = of * 16 + l4 * 4 + r;
          Y[(rbase + o) * KC_ + k * N_ + m0 + mf * 16 + l15] = f2bf(acc[of][mf][r]);
        }
  }
}

// ---------- 192x256-tile phased GEMM (r6 K-loop) + FUSED epilogue ----------
// LAYER 0: res = x (f32); writes x1 (bf16, ws) + fused mix2 -> Y2.
// LAYER 1: res = x1 (bf16); fused fc -> out (f32); x2 never hits HBM.
// FIX vs r12: phase-A row index rowb = rowb0 + rl0 + r (was missing rowb0 ->
// wrong t for 3/4 of tiles); added lgkmcnt(0) before phase-A->B barrier
// (ds_write visibility race; K-loop never needed it since it stages via vmcnt).

#define MFMA12G(g, A, Bv)                                                                       \
  acc[3*(g)+0][0] = __builtin_amdgcn_mfma_f32_16x16x32_bf16(A[0], Bv[0], acc[3*(g)+0][0],0,0,0); \
  acc[3*(g)+0][1] = __builtin_amdgcn_mfma_f32_16x16x32_bf16(A[0], Bv[1], acc[3*(g)+0][1],0,0,0); \
  acc[3*(g)+0][2] = __builtin_amdgcn_mfma_f32_16x16x32_bf16(A[0], Bv[2], acc[3*(g)+0][2],0,0,0); \
  acc[3*(g)+0][3] = __builtin_amdgcn_mfma_f32_16x16x32_bf16(A[0], Bv[3], acc[3*(g)+0][3],0,0,0); \
  acc[3*(g)+1][0] = __builtin_amdgcn_mfma_f32_16x16x32_bf16(A[1], Bv[0], acc[3*(g)+1][0],0,0,0); \
  acc[3*(g)+1][1] = __builtin_amdgcn_mfma_f32_16x16x32_bf16(A[1], Bv[1], acc[3*(g)+1][1],0,0,0); \
  acc[3*(g)+1][2] = __builtin_amdgcn_mfma_f32_16x16x32_bf16(A[1], Bv[2], acc[3*(g)+1][2],0,0,0); \
  acc[3*(g)+1][3] = __builtin_amdgcn_mfma_f32_16x16x32_bf16(A[1], Bv[3], acc[3*(g)+1][3],0,0,0); \
  acc[3*(g)+2][0] = __builtin_amdgcn_mfma_f32_16x16x32_bf16(A[2], Bv[0], acc[3*(g)+2][0],0,0,0); \
  acc[3*(g)+2][1] = __builtin_amdgcn_mfma_f32_16x16x32_bf16(A[2], Bv[1], acc[3*(g)+2][1],0,0,0); \
  acc[3*(g)+2][2] = __builtin_amdgcn_mfma_f32_16x16x32_bf16(A[2], Bv[2], acc[3*(g)+2][2],0,0,0); \
  acc[3*(g)+2][3] = __builtin_amdgcn_mfma_f32_16x16x32_bf16(A[2], Bv[3], acc[3*(g)+2][3],0,0,0);

#define STAGE_A(kt, j) gload16(gA##j + (size_t)(kt) * 64,                                   \
    (ushort_t*)(lp + (((kt) & 1) ? LBUF : 0) + (j) * 8192 + wofs))
#define STAGE_B(kt, j) gload16(gB##j + (size_t)(kt) * 64,                                   \
    (ushort_t*)(lp + (((kt) & 1) ? LBUF : 0) + ABYT + (j) * 8192 + wofs))

#define LD8(p) (*(const short8*)(p))

template<int LAYER>
__global__ __launch_bounds__(512)
void gemm8p(const ushort_t* __restrict__ Y, const ushort_t* __restrict__ Bt,
            const void* __restrict__ res, const float* __restrict__ bias,
            ushort_t* __restrict__ x1out,            // L0: x1 (ws, bf16); L1: unused
            const void* __restrict__ wgt,            // L0: thA2 (bf16); L1: fw (f32)
            const float* __restrict__ fb,            // L1: fc bias; L0: unused
            void* __restrict__ fout,                 // L0: Y2 (bf16); L1: out (f32)
            int batch0) {
  const int nwg = gridDim.x;
  int orig = blockIdx.x;
  int q8 = nwg >> 3;
  int wg = (orig & 7) * q8 + (orig >> 3);
  const int mtile = wg >> 2, ntile = wg & 3;

  const int tid = threadIdx.x;
  const int wid = tid >> 6, lane = tid & 63;
  const int wm = wid >> 2, wn = wid & 3;
  const int l15 = lane & 15, l4 = lane >> 4;

  __shared__ ushort_t LDSU[LBUF];   // 114688 bytes total (2 buffers)
  char* lp = (char*)LDSU;

  const int row0 = mtile * BM_;
  const int n0 = ntile * 256;
  const int wofs = wid * 1024;

  const int lam = lane >> 2, lc = lane & 3;
  const ushort_t *gA0, *gA1, *gA2, *gB0, *gB1, *gB2, *gB3;
  {
    int p, s, row, colel;
    p = 0 * 128 + wid * 16 + lam; s = p >= 192 ? 1 : 0; row = p - s * 192;
    colel = (lc * 8) ^ (((row >> 3) & 1) << 4);
    gA0 = Y + (size_t)(row0 + row) * KC_ + s * 32 + colel;
    p = 1 * 128 + wid * 16 + lam; s = p >= 192 ? 1 : 0; row = p - s * 192;
    colel = (lc * 8) ^ (((row >> 3) & 1) << 4);
    gA1 = Y + (size_t)(row0 + row) * KC_ + s * 32 + colel;
    p = 2 * 128 + wid * 16 + lam; s = p >= 192 ? 1 : 0; row = p - s * 192;
    colel = (lc * 8) ^ (((row >> 3) & 1) << 4);
    gA2 = Y + (size_t)(row0 + row) * KC_ + s * 32 + colel;
    p = 0 * 128 + wid * 16 + lam; s = p >> 8; row = p & 255;
    colel = (lc * 8) ^ (((row >> 3) & 1) << 4);
    gB0 = Bt + (size_t)(n0 + row) * KC_ + s * 32 + colel;
    p = 1 * 128 + wid * 16 + lam; s = p >> 8; row = p & 255;
    colel = (lc * 8) ^ (((row >> 3) & 1) << 4);
    gB1 = Bt + (size_t)(n0 + row) * KC_ + s * 32 + colel;
    p = 2 * 128 + wid * 16 + lam; s = p >> 8; row = p & 255;
    colel = (lc * 8) ^ (((row >> 3) & 1) << 4);
    gB2 = Bt + (size_t)(n0 + row) * KC_ + s * 32 + colel;
    p = 3 * 128 + wid * 16 + lam; s = p >> 8; row = p & 255;
    colel = (lc * 8) ^ (((row >> 3) & 1) << 4);
    gB3 = Bt + (size_t)(n0 + row) * KC_ + s * 32 + colel;
  }

  const int swz = ((l15 >> 3) & 1) << 5;
  const int a_base = (wm * 16 + l15) * 64 + ((l4 * 16) ^ swz);
  const int b_base = ABYT + (wn * 16 + l15) * 64 + ((l4 * 16) ^ swz);

  // prologue: tile0 fully, tile1 minus A2 (13 units); vmcnt(6) -> tile0 landed
  STAGE_B(0, 0); STAGE_B(0, 1); STAGE_B(0, 2); STAGE_B(0, 3);
  STAGE_A(0, 0); STAGE_A(0, 1); STAGE_A(0, 2);
  STAGE_B(1, 0); STAGE_B(1, 1); STAGE_B(1, 2); STAGE_B(1, 3);
  STAGE_A(1, 0); STAGE_A(1, 1);
  asm volatile("s_waitcnt vmcnt(6)" ::: "memory");
  __builtin_amdgcn_s_barrier();
  __builtin_amdgcn_sched_barrier(0);

  f32x4 acc[6][4] = {};
  short8 aA[3], aB[3], bS0[4], bS1[4];

  { // pre-read G0(0): A s0 m0-2 + B s0
    const char* abp = lp + a_base;
    const char* bbp = lp + b_base;
    aA[0] = LD8(abp);          aA[1] = LD8(abp + 2048);   aA[2] = LD8(abp + 4096);
    bS0[0] = LD8(bbp);         bS0[1] = LD8(bbp + 4096);
    bS0[2] = LD8(bbp + 8192);  bS0[3] = LD8(bbp + 12288);
  }

  for (int u = 0; u < NT_; ++u) {
    const char* abp = lp + ((u & 1) ? LBUF : 0) + a_base;
    const char* bbp = lp + ((u & 1) ? LBUF : 0) + b_base;
    const char* abn = lp + ((u & 1) ? 0 : LBUF) + a_base;
    const char* bbn = lp + ((u & 1) ? 0 : LBUF) + b_base;

    { // phase 0: MFMA(G0) ; read G1 ; stage A2(u+1)
      if (u + 1 < NT_) STAGE_A(u + 1, 2);
      __builtin_amdgcn_s_barrier();
      __builtin_amdgcn_sched_barrier(0);
      aB[0] = LD8(abp + 6144); aB[1] = LD8(abp + 8192); aB[2] = LD8(abp + 10240);
      __builtin_amdgcn_sched_barrier(0);
      __builtin_amdgcn_s_setprio(1);
      MFMA12G(0, aA, bS0)
      __builtin_amdgcn_s_setprio(0);
      __builtin_amdgcn_s_barrier();
    }
    { // phase 1: MFMA(G1) ; read G2 ; stage B0,B1(u+2)
      if (u + 2 < NT_) { STAGE_B(u + 2, 0); STAGE_B(u + 2, 1); }
      __builtin_amdgcn_s_barrier();
      __builtin_amdgcn_sched_barrier(0);
      aA[0] = LD8(abp + 12288);         aA[1] = LD8(abp + 12288 + 2048);
      aA[2] = LD8(abp + 12288 + 4096);
      bS1[0] = LD8(bbp + BPLN);         bS1[1] = LD8(bbp + BPLN + 4096);
      bS1[2] = LD8(bbp + BPLN + 8192);  bS1[3] = LD8(bbp + BPLN + 12288);
      __builtin_amdgcn_sched_barrier(0);
      __builtin_amdgcn_s_setprio(1);
      MFMA12G(1, aB, bS0)
      __builtin_amdgcn_s_setprio(0);
      __builtin_amdgcn_s_barrier();
    }
    { // phase 2: MFMA(G2) ; read G3
      __builtin_amdgcn_s_barrier();
      __builtin_amdgcn_sched_barrier(0);
      aB[0] = LD8(abp + 12288 + 6144);
      aB[1] = LD8(abp + 12288 + 8192);
      aB[2] = LD8(abp + 12288 + 10240);
      __builtin_amdgcn_sched_barrier(0);
      __builtin_amdgcn_s_setprio(1);
      MFMA12G(0, aA, bS1)
      __builtin_amdgcn_s_setprio(0);
      __builtin_amdgcn_s_barrier();
    }
    { // phase 3: MFMA(G3) ; stage B2,B3,A0,A1(u+2) ; vmcnt ; read G0(u+1)
      if (u + 2 < NT_) {
        STAGE_B(u + 2, 2); STAGE_B(u + 2, 3);
        STAGE_A(u + 2, 0); STAGE_A(u + 2, 1);
        asm volatile("s_waitcnt vmcnt(6)" ::: "memory");
      } else if (u + 2 == NT_) {
        asm volatile("s_waitcnt vmcnt(0)" ::: "memory");
      }
      __builtin_amdgcn_s_barrier();
      __builtin_amdgcn_sched_barrier(0);
      if (u + 1 < NT_) {
        aA[0] = LD8(abn);          aA[1] = LD8(abn + 2048);   aA[2] = LD8(abn + 4096);
        bS0[0] = LD8(bbn);         bS0[1] = LD8(bbn + 4096);
        bS0[2] = LD8(bbn + 8192);  bS0[3] = LD8(bbn + 12288);
      }
      __builtin_amdgcn_sched_barrier(0);
      __builtin_amdgcn_s_setprio(1);
      MFMA12G(1, aB, bS1)
      __builtin_amdgcn_s_setprio(0);
      __builtin_amdgcn_s_barrier();
    }
  }

  // ---- fused epilogue, phase A: bias+residual+relu; x-tile -> LDS [bt][n][i] ----
  // (loop ended with s_barrier; all LDS reads complete -> safe to overwrite)
  const float*    resf = (const float*)res;
  const ushort_t* resb = (const ushort_t*)res;
  const int gb = batch0 + (mtile >> 2);
  const int rowb0 = (mtile & 3) * BM_;
  const int tloc = (mtile & 3) * 3;        // t-subindex base of bt_local
  #pragma unroll
  for (int mf = 0; mf < 6; ++mf) {
    const int rl0 = mf * 32 + wm * 16 + l4 * 4;
    const int btl = rl0 >> 6;              // same for r=0..3
    const int i0  = rl0 & 63;
    #pragma unroll
    for (int nf = 0; nf < 4; ++nf) {
      const int nl = wn * 16 + nf * 64 + l15;
      const int col = n0 + nl;
      u64 pack = 0;
      #pragma unroll
      for (int r = 0; r < 4; ++r) {
        int rowb = rowb0 + rl0 + r;        // FIX: global row within batch
        int t = rowb >> 6, o = rowb & 63;
        size_t base = ((size_t)(gb * C_ + o) * T_ + t) * N_;
        float rv = (LAYER == 0) ? resf[base + col] : bf2f(resb[base + col]);
        float v = fmaxf(acc[mf][nf][r] + bias[o] + rv, 0.0f);
        ushort_t bv = f2bf(v);
        if (LAYER == 0) x1out[base + col] = bv;
        pack |= (u64)bv << (16 * r);
      }
      int byte = btl * 32768 + nl * 128 + i0 * 2;
      byte ^= ((nl & 7) << 4);
      *(u64*)(lp + byte) = pack;
    }
  }
  asm volatile("s_waitcnt lgkmcnt(0)" ::: "memory");   // FIX: drain ds_writes
  __builtin_amdgcn_sched_barrier(0);
  __builtin_amdgcn_s_barrier();

  // ---- fused epilogue, phase B: small MFMA against L2-hot weights ----
  if (LAYER == 0) {
    // mix2: Y2[(chunk-local bt)*64 + o2][kk*1024 + m]
    const ushort_t* th2 = (const ushort_t*)wgt;
    ushort_t* y2 = (ushort_t*)fout;
    const int y2tb = (mtile >> 2) * RPB + tloc * 64;
    #pragma unroll
    for (int kk = 0; kk < 3; ++kk) {
      short8 afr[2][2];
      #pragma unroll
      for (int f = 0; f < 2; ++f)
        #pragma unroll
        for (int ks = 0; ks < 2; ++ks)
          afr[f][ks] = *(const short8*)&th2[((size_t)kk * 64 + (wm * 2 + f) * 16 + l15) * 64 + ks * 32 + l4 * 8];
      f32x4 a2[3][2][4] = {};
      #pragma unroll
      for (int bt = 0; bt < 3; ++bt)
        #pragma unroll
        for (int ks = 0; ks < 2; ++ks)
          #pragma unroll
          for (int nf = 0; nf < 4; ++nf) {
            const int nl = wn * 16 + nf * 64 + l15;
            int byte = bt * 32768 + nl * 128 + (ks * 32 + l4 * 8) * 2;
            byte ^= ((nl & 7) << 4);
            short8 bfr = LD8(lp + byte);
            #pragma unroll
            for (int f = 0; f < 2; ++f)
              a2[bt][f][nf] = __builtin_amdgcn_mfma_f32_16x16x32_bf16(afr[f][ks], bfr, a2[bt][f][nf], 0, 0, 0);
          }
      #pragma unroll
      for (int bt = 0; bt < 3; ++bt)
        #pragma unroll
        for (int f = 0; f < 2; ++f)
          #pragma unroll
          for (int nf = 0; nf < 4; ++nf) {
            const int m = n0 + wn * 16 + nf * 64 + l15;
            const int o2b = (wm * 2 + f) * 16 + l4 * 4;
            const size_t rbase = (size_t)(y2tb + bt * 64 + o2b);
            #pragma unroll
            for (int r = 0; r < 4; ++r)
              y2[(rbase + r) * KC_ + kk * N_ + m] = f2bf(a2[bt][f][nf][r]);
          }
    }
  } else {
    // fc: out[((gb*12 + t)*1024 + n)*64 + o2]
    const float* fw = (const float*)wgt;
    float* outf = (float*)fout;
    short8 afr[2][2];
    #pragma unroll
    for (int f = 0; f < 2; ++f)
      #pragma unroll
      for (int ks = 0; ks < 2; ++ks) {
        const float* wsrc = fw + ((wm * 2 + f) * 16 + l15) * 64 + ks * 32 + l4 * 8;
        float4 wa = *(const float4*)wsrc;
        float4 wb = *(const float4*)(wsrc + 4);
        short8 w8;
        w8[0] = (short)f2bf(wa.x); w8[1] = (short)f2bf(wa.y);
        w8[2] = (short)f2bf(wa.z); w8[3] = (short)f2bf(wa.w);
        w8[4] = (short)f2bf(wb.x); w8[5] = (short)f2bf(wb.y);
        w8[6] = (short)f2bf(wb.z); w8[7] = (short)f2bf(wb.w);
        afr[f][ks] = w8;
      }
    f32x4 a2[3][2][4] = {};
    #pragma unroll
    for (int bt = 0; bt < 3; ++bt)
      #pragma unroll
      for (int ks = 0; ks < 2; ++ks)
        #pragma unroll
        for (int nf = 0; nf < 4; ++nf) {
          const int nl = wn * 16 + nf * 64 + l15;
          int byte = bt * 32768 + nl * 128 + (ks * 32 + l4 * 8) * 2;
          byte ^= ((nl & 7) << 4);
          short8 bfr = LD8(lp + byte);
          #pragma unroll
          for (int f = 0; f < 2; ++f)
            a2[bt][f][nf] = __builtin_amdgcn_mfma_f32_16x16x32_bf16(afr[f][ks], bfr, a2[bt][f][nf], 0, 0, 0);
        }
    #pragma unroll
    for (int bt = 0; bt < 3; ++bt)
      #pragma unroll
      for (int f = 0; f < 2; ++f)
        #pragma unroll
        for (int nf = 0; nf < 4; ++nf) {
          const int n = n0 + wn * 16 + nf * 64 + l15;
          const int o2b = (wm * 2 + f) * 16 + l4 * 4;
          float4 fb4 = *(const float4*)&fb[o2b];
          const size_t btg = (size_t)(gb * 12 + tloc + bt);
          float4 v;
          v.x = a2[bt][f][nf][0] + fb4.x;
          v.y = a2[bt][f][nf][1] + fb4.y;
          v.z = a2[bt][f][nf][2] + fb4.z;
          v.w = a2[bt][f][nf][3] + fb4.w;
          *(float4*)&outf[(btg * 1024 + n) * 64 + o2b] = v;
        }
  }
}

extern "C" void kernel_launch(void* const* d_in, const int* in_sizes, int n_in,
                              void* d_out, int out_size, void* d_ws, size_t ws_size,
                              hipStream_t stream) {
  const float* x   = (const float*)d_in[0];
  const float* Lk  = (const float*)d_in[1];
  const float* th1 = (const float*)d_in[2];
  const float* b1  = (const float*)d_in[3];
  const float* th2 = (const float*)d_in[4];
  const float* b2  = (const float*)d_in[5];
  const float* fcw = (const float*)d_in[6];
  const float* fcb = (const float*)d_in[7];

  char* ws = (char*)d_ws;
  size_t off = 0;
  auto alloc = [&](size_t bytes) { size_t p = off; off += (bytes + 255) & ~(size_t)255; return p; };
  size_t oBt = alloc((size_t)KC_ * N_ * 2);            // 6.29 MB
  size_t oTh = alloc((size_t)2 * 3 * 64 * 64 * 2);     // 48 KB
  size_t oX1 = alloc((size_t)B_ * C_ * T_ * N_ * 2);   // 50.3 MB (x1 scratch)
  size_t perY = (size_t)RPB * KC_ * 2;                 // 4.72 MB per batch per Y buffer
  size_t avail = ws_size > off ? ws_size - off : 0;
  int NB = (int)(avail / (2 * perY));                  // two Y buffers
  if (NB > B_) NB = B_;
  if (NB < 1) NB = 1;

  ushort_t* Bt  = (ushort_t*)(ws + oBt);
  ushort_t* Th  = (ushort_t*)(ws + oTh);
  ushort_t* X1  = (ushort_t*)(ws + oX1);
  ushort_t* Yb1 = (ushort_t*)(ws + off);
  ushort_t* Yb2 = Yb1 + (size_t)NB * RPB * KC_;

  prep_th<<<96, 256, 0, stream>>>(th1, th2, Th);
  prep_bt<<<1536, 256, 0, stream>>>(Lk, Bt);

  for (int b0 = 0; b0 < B_; b0 += NB) {
    int nb = (b0 + NB <= B_) ? NB : (B_ - b0);
    // layer-1 mix: x -> Y1
    mix_mfma<<<nb * 48, 256, 0, stream>>>(x, Th, Yb1, b0);
    // layer-1 gemm + fused mix2: Y1 -> x1 (ws) + Y2
    gemm8p<0><<<dim3(16 * nb), 512, 0, stream>>>(
        Yb1, Bt, (const void*)x, b1, X1, (const void*)(Th + 12288), fcb, (void*)Yb2, b0);
    // layer-2 gemm + fused fc: Y2 -> out (x2 never materialized)
    gemm8p<1><<<dim3(16 * nb), 512, 0, stream>>>(
        Yb2, Bt, (const void*)X1, b2, X1, (const void*)fcw, fcb, d_out, b0);
  }
}

// Round 15
// 418.278 us; speedup vs baseline: 1.3502x; 1.0624x over previous
//
#include <hip/hip_runtime.h>

typedef unsigned short ushort_t;
typedef unsigned long long u64;
typedef short short8 __attribute__((ext_vector_type(8)));
typedef float f32x4 __attribute__((ext_vector_type(4)));

#define B_   32
#define C_   64
#define T_   12
#define N_   1024
#define KS_  3
#define KC_  3072
#define RPB  768
#define NT_  48          // K-tiles of 64
#define BM_  192
#define LBUF 57344       // bytes per LDS buffer: A 192*64*2 (=24576) + B 256*64*2 (=32768)
#define ABYT 24576       // A region bytes
#define BPLN 16384       // B plane stride

__device__ __forceinline__ float bf2f(ushort_t u) {
  union { unsigned u; float f; } v; v.u = ((unsigned)u) << 16; return v.f;
}
__device__ __forceinline__ ushort_t f2bf(float f) {
  union { float f; unsigned u; } v; v.f = f;
  unsigned r = v.u + 0x7FFFu + ((v.u >> 16) & 1u);
  return (ushort_t)(r >> 16);
}

__device__ __forceinline__ void gload16(const ushort_t* g, ushort_t* l) {
  __builtin_amdgcn_global_load_lds(
      (const __attribute__((address_space(1))) unsigned int*)g,
      (__attribute__((address_space(3))) unsigned int*)l, 16, 0, 0);
}

// ---------- prep: thA[l][k][o][i] = bf16(theta_l[i][o][k]) ----------
__global__ void prep_th(const float* __restrict__ th1, const float* __restrict__ th2,
                        ushort_t* __restrict__ out) {
  int id = blockIdx.x * 256 + threadIdx.x;          // 2*3*64*64 = 24576
  if (id >= 24576) return;
  int l = id / 12288, rem = id % 12288;
  int k = rem / 4096;
  int o = (rem >> 6) & 63;
  int i = rem & 63;
  const float* th = l ? th2 : th1;
  out[id] = f2bf(th[(i * 64 + o) * 3 + k]);
}

// ---------- prep: Bt[n][k*1024+m] = bf16(Lk[k][n][m]) ----------
__global__ void prep_bt(const float* __restrict__ Lk, ushort_t* __restrict__ Bt) {
  int id = blockIdx.x * 256 + threadIdx.x;
  int k = id >> 17, rem = id & 131071;
  int n = rem >> 7, mc = rem & 127;
  int m = mc << 3;
  const float* src = Lk + ((k * N_ + n) * N_ + m);
  float4 v0 = *(const float4*)src;
  float4 v1 = *(const float4*)(src + 4);
  short8 o8;
  o8[0] = (short)f2bf(v0.x); o8[1] = (short)f2bf(v0.y);
  o8[2] = (short)f2bf(v0.z); o8[3] = (short)f2bf(v0.w);
  o8[4] = (short)f2bf(v1.x); o8[5] = (short)f2bf(v1.y);
  o8[6] = (short)f2bf(v1.z); o8[7] = (short)f2bf(v1.w);
  *(short8*)&Bt[n * KC_ + k * N_ + m] = o8;
}

// ---------- MFMA channel mix (layer 1 only: fp32 input) ----------
__global__ __launch_bounds__(256, 2)
void mix_mfma(const float* __restrict__ xg_f, const ushort_t* __restrict__ thA,
              ushort_t* __restrict__ Y, int b0) {
  const int bid = blockIdx.x;           // nb*48: [bt][mq]
  const int mq = bid & 3;
  const int bt = bid >> 2;              // bl*12 + t
  const int bl = bt / 12, t = bt % 12;
  const int b = b0 + bl;
  const int tid = threadIdx.x;
  const int wv = tid >> 6, lane = tid & 63;
  const int l15 = lane & 15, l4 = lane >> 4;
  const int m0 = mq * 256 + wv * 64;

  short8 bfr[4][2];
  #pragma unroll
  for (int mf = 0; mf < 4; ++mf) {
    const int m = m0 + mf * 16 + l15;
    #pragma unroll
    for (int ks = 0; ks < 2; ++ks) {
      #pragma unroll
      for (int j = 0; j < 8; ++j) {
        const int i = ks * 32 + l4 * 8 + j;
        const size_t adr = ((size_t)(b * C_ + i) * T_ + t) * N_ + m;
        bfr[mf][ks][j] = (short)f2bf(xg_f[adr]);
      }
    }
  }

  const size_t rbase = (size_t)(bt * C_);
  #pragma unroll
  for (int k = 0; k < 3; ++k) {
    short8 afr[4][2];
    #pragma unroll
    for (int of = 0; of < 4; ++of)
      #pragma unroll
      for (int ks = 0; ks < 2; ++ks)
        afr[of][ks] = *(const short8*)&thA[(size_t)(k * 64 + of * 16 + l15) * 64 + ks * 32 + l4 * 8];

    f32x4 acc[4][4] = {};
    #pragma unroll
    for (int ks = 0; ks < 2; ++ks)
      #pragma unroll
      for (int of = 0; of < 4; ++of)
        #pragma unroll
        for (int mf = 0; mf < 4; ++mf)
          acc[of][mf] = __builtin_amdgcn_mfma_f32_16x16x32_bf16(afr[of][ks], bfr[mf][ks], acc[of][mf], 0, 0, 0);

    #pragma unroll
    for (int of = 0; of < 4; ++of)
      #pragma unroll
      for (int mf = 0; mf < 4; ++mf)
        #pragma unroll
        for (int r = 0; r < 4; ++r) {
          const int o = of * 16 + l4 * 4 + r;
          Y[(rbase + o) * KC_ + k * N_ + m0 + mf * 16 + l15] = f2bf(acc[of][mf][r]);
        }
  }
}

// ---------- 192x256-tile phased GEMM (r6 K-loop) + FUSED epilogue ----------
// LAYER 0: res = x (f32); writes x1 (bf16, ws) + fused mix2 -> Y2.
// LAYER 1: res = x1 (bf16); fused fc -> out (f32); x2 never hits HBM.
// r14 change: NB capped at 16 so each Y chunk (75.5 MB) is L3-resident between
// producer and consumer dispatch -> K-loop stage latency ~200-400cyc (L3) instead
// of ~900 (HBM), closing the phase-3 vmcnt(6) exposure. Kernel body unchanged.

#define MFMA12G(g, A, Bv)                                                                       \
  acc[3*(g)+0][0] = __builtin_amdgcn_mfma_f32_16x16x32_bf16(A[0], Bv[0], acc[3*(g)+0][0],0,0,0); \
  acc[3*(g)+0][1] = __builtin_amdgcn_mfma_f32_16x16x32_bf16(A[0], Bv[1], acc[3*(g)+0][1],0,0,0); \
  acc[3*(g)+0][2] = __builtin_amdgcn_mfma_f32_16x16x32_bf16(A[0], Bv[2], acc[3*(g)+0][2],0,0,0); \
  acc[3*(g)+0][3] = __builtin_amdgcn_mfma_f32_16x16x32_bf16(A[0], Bv[3], acc[3*(g)+0][3],0,0,0); \
  acc[3*(g)+1][0] = __builtin_amdgcn_mfma_f32_16x16x32_bf16(A[1], Bv[0], acc[3*(g)+1][0],0,0,0); \
  acc[3*(g)+1][1] = __builtin_amdgcn_mfma_f32_16x16x32_bf16(A[1], Bv[1], acc[3*(g)+1][1],0,0,0); \
  acc[3*(g)+1][2] = __builtin_amdgcn_mfma_f32_16x16x32_bf16(A[1], Bv[2], acc[3*(g)+1][2],0,0,0); \
  acc[3*(g)+1][3] = __builtin_amdgcn_mfma_f32_16x16x32_bf16(A[1], Bv[3], acc[3*(g)+1][3],0,0,0); \
  acc[3*(g)+2][0] = __builtin_amdgcn_mfma_f32_16x16x32_bf16(A[2], Bv[0], acc[3*(g)+2][0],0,0,0); \
  acc[3*(g)+2][1] = __builtin_amdgcn_mfma_f32_16x16x32_bf16(A[2], Bv[1], acc[3*(g)+2][1],0,0,0); \
  acc[3*(g)+2][2] = __builtin_amdgcn_mfma_f32_16x16x32_bf16(A[2], Bv[2], acc[3*(g)+2][2],0,0,0); \
  acc[3*(g)+2][3] = __builtin_amdgcn_mfma_f32_16x16x32_bf16(A[2], Bv[3], acc[3*(g)+2][3],0,0,0);

#define STAGE_A(kt, j) gload16(gA##j + (size_t)(kt) * 64,                                   \
    (ushort_t*)(lp + (((kt) & 1) ? LBUF : 0) + (j) * 8192 + wofs))
#define STAGE_B(kt, j) gload16(gB##j + (size_t)(kt) * 64,                                   \
    (ushort_t*)(lp + (((kt) & 1) ? LBUF : 0) + ABYT + (j) * 8192 + wofs))

#define LD8(p) (*(const short8*)(p))

template<int LAYER>
__global__ __launch_bounds__(512)
void gemm8p(const ushort_t* __restrict__ Y, const ushort_t* __restrict__ Bt,
            const void* __restrict__ res, const float* __restrict__ bias,
            ushort_t* __restrict__ x1out,            // L0: x1 (ws, bf16); L1: unused
            const void* __restrict__ wgt,            // L0: thA2 (bf16); L1: fw (f32)
            const float* __restrict__ fb,            // L1: fc bias; L0: unused
            void* __restrict__ fout,                 // L0: Y2 (bf16); L1: out (f32)
            int batch0) {
  const int nwg = gridDim.x;
  int orig = blockIdx.x;
  int q8 = nwg >> 3;
  int wg = (orig & 7) * q8 + (orig >> 3);
  const int mtile = wg >> 2, ntile = wg & 3;

  const int tid = threadIdx.x;
  const int wid = tid >> 6, lane = tid & 63;
  const int wm = wid >> 2, wn = wid & 3;
  const int l15 = lane & 15, l4 = lane >> 4;

  __shared__ ushort_t LDSU[LBUF];   // 114688 bytes total (2 buffers)
  char* lp = (char*)LDSU;

  const int row0 = mtile * BM_;
  const int n0 = ntile * 256;
  const int wofs = wid * 1024;

  const int lam = lane >> 2, lc = lane & 3;
  const ushort_t *gA0, *gA1, *gA2, *gB0, *gB1, *gB2, *gB3;
  {
    int p, s, row, colel;
    p = 0 * 128 + wid * 16 + lam; s = p >= 192 ? 1 : 0; row = p - s * 192;
    colel = (lc * 8) ^ (((row >> 3) & 1) << 4);
    gA0 = Y + (size_t)(row0 + row) * KC_ + s * 32 + colel;
    p = 1 * 128 + wid * 16 + lam; s = p >= 192 ? 1 : 0; row = p - s * 192;
    colel = (lc * 8) ^ (((row >> 3) & 1) << 4);
    gA1 = Y + (size_t)(row0 + row) * KC_ + s * 32 + colel;
    p = 2 * 128 + wid * 16 + lam; s = p >= 192 ? 1 : 0; row = p - s * 192;
    colel = (lc * 8) ^ (((row >> 3) & 1) << 4);
    gA2 = Y + (size_t)(row0 + row) * KC_ + s * 32 + colel;
    p = 0 * 128 + wid * 16 + lam; s = p >> 8; row = p & 255;
    colel = (lc * 8) ^ (((row >> 3) & 1) << 4);
    gB0 = Bt + (size_t)(n0 + row) * KC_ + s * 32 + colel;
    p = 1 * 128 + wid * 16 + lam; s = p >> 8; row = p & 255;
    colel = (lc * 8) ^ (((row >> 3) & 1) << 4);
    gB1 = Bt + (size_t)(n0 + row) * KC_ + s * 32 + colel;
    p = 2 * 128 + wid * 16 + lam; s = p >> 8; row = p & 255;
    colel = (lc * 8) ^ (((row >> 3) & 1) << 4);
    gB2 = Bt + (size_t)(n0 + row) * KC_ + s * 32 + colel;
    p = 3 * 128 + wid * 16 + lam; s = p >> 8; row = p & 255;
    colel = (lc * 8) ^ (((row >> 3) & 1) << 4);
    gB3 = Bt + (size_t)(n0 + row) * KC_ + s * 32 + colel;
  }

  const int swz = ((l15 >> 3) & 1) << 5;
  const int a_base = (wm * 16 + l15) * 64 + ((l4 * 16) ^ swz);
  const int b_base = ABYT + (wn * 16 + l15) * 64 + ((l4 * 16) ^ swz);

  // prologue: tile0 fully, tile1 minus A2 (13 units); vmcnt(6) -> tile0 landed
  STAGE_B(0, 0); STAGE_B(0, 1); STAGE_B(0, 2); STAGE_B(0, 3);
  STAGE_A(0, 0); STAGE_A(0, 1); STAGE_A(0, 2);
  STAGE_B(1, 0); STAGE_B(1, 1); STAGE_B(1, 2); STAGE_B(1, 3);
  STAGE_A(1, 0); STAGE_A(1, 1);
  asm volatile("s_waitcnt vmcnt(6)" ::: "memory");
  __builtin_amdgcn_s_barrier();
  __builtin_amdgcn_sched_barrier(0);

  f32x4 acc[6][4] = {};
  short8 aA[3], aB[3], bS0[4], bS1[4];

  { // pre-read G0(0): A s0 m0-2 + B s0
    const char* abp = lp + a_base;
    const char* bbp = lp + b_base;
    aA[0] = LD8(abp);          aA[1] = LD8(abp + 2048);   aA[2] = LD8(abp + 4096);
    bS0[0] = LD8(bbp);         bS0[1] = LD8(bbp + 4096);
    bS0[2] = LD8(bbp + 8192);  bS0[3] = LD8(bbp + 12288);
  }

  for (int u = 0; u < NT_; ++u) {
    const char* abp = lp + ((u & 1) ? LBUF : 0) + a_base;
    const char* bbp = lp + ((u & 1) ? LBUF : 0) + b_base;
    const char* abn = lp + ((u & 1) ? 0 : LBUF) + a_base;
    const char* bbn = lp + ((u & 1) ? 0 : LBUF) + b_base;

    { // phase 0: MFMA(G0) ; read G1 ; stage A2(u+1)
      if (u + 1 < NT_) STAGE_A(u + 1, 2);
      __builtin_amdgcn_s_barrier();
      __builtin_amdgcn_sched_barrier(0);
      aB[0] = LD8(abp + 6144); aB[1] = LD8(abp + 8192); aB[2] = LD8(abp + 10240);
      __builtin_amdgcn_sched_barrier(0);
      __builtin_amdgcn_s_setprio(1);
      MFMA12G(0, aA, bS0)
      __builtin_amdgcn_s_setprio(0);
      __builtin_amdgcn_s_barrier();
    }
    { // phase 1: MFMA(G1) ; read G2 ; stage B0,B1(u+2)
      if (u + 2 < NT_) { STAGE_B(u + 2, 0); STAGE_B(u + 2, 1); }
      __builtin_amdgcn_s_barrier();
      __builtin_amdgcn_sched_barrier(0);
      aA[0] = LD8(abp + 12288);         aA[1] = LD8(abp + 12288 + 2048);
      aA[2] = LD8(abp + 12288 + 4096);
      bS1[0] = LD8(bbp + BPLN);         bS1[1] = LD8(bbp + BPLN + 4096);
      bS1[2] = LD8(bbp + BPLN + 8192);  bS1[3] = LD8(bbp + BPLN + 12288);
      __builtin_amdgcn_sched_barrier(0);
      __builtin_amdgcn_s_setprio(1);
      MFMA12G(1, aB, bS0)
      __builtin_amdgcn_s_setprio(0);
      __builtin_amdgcn_s_barrier();
    }
    { // phase 2: MFMA(G2) ; read G3
      __builtin_amdgcn_s_barrier();
      __builtin_amdgcn_sched_barrier(0);
      aB[0] = LD8(abp + 12288 + 6144);
      aB[1] = LD8(abp + 12288 + 8192);
      aB[2] = LD8(abp + 12288 + 10240);
      __builtin_amdgcn_sched_barrier(0);
      __builtin_amdgcn_s_setprio(1);
      MFMA12G(0, aA, bS1)
      __builtin_amdgcn_s_setprio(0);
      __builtin_amdgcn_s_barrier();
    }
    { // phase 3: MFMA(G3) ; stage B2,B3,A0,A1(u+2) ; vmcnt ; read G0(u+1)
      if (u + 2 < NT_) {
        STAGE_B(u + 2, 2); STAGE_B(u + 2, 3);
        STAGE_A(u + 2, 0); STAGE_A(u + 2, 1);
        asm volatile("s_waitcnt vmcnt(6)" ::: "memory");
      } else if (u + 2 == NT_) {
        asm volatile("s_waitcnt vmcnt(0)" ::: "memory");
      }
      __builtin_amdgcn_s_barrier();
      __builtin_amdgcn_sched_barrier(0);
      if (u + 1 < NT_) {
        aA[0] = LD8(abn);          aA[1] = LD8(abn + 2048);   aA[2] = LD8(abn + 4096);
        bS0[0] = LD8(bbn);         bS0[1] = LD8(bbn + 4096);
        bS0[2] = LD8(bbn + 8192);  bS0[3] = LD8(bbn + 12288);
      }
      __builtin_amdgcn_sched_barrier(0);
      __builtin_amdgcn_s_setprio(1);
      MFMA12G(1, aB, bS1)
      __builtin_amdgcn_s_setprio(0);
      __builtin_amdgcn_s_barrier();
    }
  }

  // ---- fused epilogue, phase A: bias+residual+relu; x-tile -> LDS [bt][n][i] ----
  const float*    resf = (const float*)res;
  const ushort_t* resb = (const ushort_t*)res;
  const int gb = batch0 + (mtile >> 2);
  const int rowb0 = (mtile & 3) * BM_;
  const int tloc = (mtile & 3) * 3;        // t-subindex base of bt_local
  #pragma unroll
  for (int mf = 0; mf < 6; ++mf) {
    const int rl0 = mf * 32 + wm * 16 + l4 * 4;
    const int btl = rl0 >> 6;
    const int i0  = rl0 & 63;
    #pragma unroll
    for (int nf = 0; nf < 4; ++nf) {
      const int nl = wn * 16 + nf * 64 + l15;
      const int col = n0 + nl;
      u64 pack = 0;
      #pragma unroll
      for (int r = 0; r < 4; ++r) {
        int rowb = rowb0 + rl0 + r;        // global row within batch
        int t = rowb >> 6, o = rowb & 63;
        size_t base = ((size_t)(gb * C_ + o) * T_ + t) * N_;
        float rv = (LAYER == 0) ? resf[base + col] : bf2f(resb[base + col]);
        float v = fmaxf(acc[mf][nf][r] + bias[o] + rv, 0.0f);
        ushort_t bv = f2bf(v);
        if (LAYER == 0) x1out[base + col] = bv;
        pack |= (u64)bv << (16 * r);
      }
      int byte = btl * 32768 + nl * 128 + i0 * 2;
      byte ^= ((nl & 7) << 4);
      *(u64*)(lp + byte) = pack;
    }
  }
  asm volatile("s_waitcnt lgkmcnt(0)" ::: "memory");   // drain ds_writes
  __builtin_amdgcn_sched_barrier(0);
  __builtin_amdgcn_s_barrier();

  // ---- fused epilogue, phase B: small MFMA against L2-hot weights ----
  if (LAYER == 0) {
    const ushort_t* th2 = (const ushort_t*)wgt;
    ushort_t* y2 = (ushort_t*)fout;
    const int y2tb = (mtile >> 2) * RPB + tloc * 64;
    #pragma unroll
    for (int kk = 0; kk < 3; ++kk) {
      short8 afr[2][2];
      #pragma unroll
      for (int f = 0; f < 2; ++f)
        #pragma unroll
        for (int ks = 0; ks < 2; ++ks)
          afr[f][ks] = *(const short8*)&th2[((size_t)kk * 64 + (wm * 2 + f) * 16 + l15) * 64 + ks * 32 + l4 * 8];
      f32x4 a2[3][2][4] = {};
      #pragma unroll
      for (int bt = 0; bt < 3; ++bt)
        #pragma unroll
        for (int ks = 0; ks < 2; ++ks)
          #pragma unroll
          for (int nf = 0; nf < 4; ++nf) {
            const int nl = wn * 16 + nf * 64 + l15;
            int byte = bt * 32768 + nl * 128 + (ks * 32 + l4 * 8) * 2;
            byte ^= ((nl & 7) << 4);
            short8 bfr = LD8(lp + byte);
            #pragma unroll
            for (int f = 0; f < 2; ++f)
              a2[bt][f][nf] = __builtin_amdgcn_mfma_f32_16x16x32_bf16(afr[f][ks], bfr, a2[bt][f][nf], 0, 0, 0);
          }
      #pragma unroll
      for (int bt = 0; bt < 3; ++bt)
        #pragma unroll
        for (int f = 0; f < 2; ++f)
          #pragma unroll
          for (int nf = 0; nf < 4; ++nf) {
            const int m = n0 + wn * 16 + nf * 64 + l15;
            const int o2b = (wm * 2 + f) * 16 + l4 * 4;
            const size_t rbase = (size_t)(y2tb + bt * 64 + o2b);
            #pragma unroll
            for (int r = 0; r < 4; ++r)
              y2[(rbase + r) * KC_ + kk * N_ + m] = f2bf(a2[bt][f][nf][r]);
          }
    }
  } else {
    const float* fw = (const float*)wgt;
    float* outf = (float*)fout;
    short8 afr[2][2];
    #pragma unroll
    for (int f = 0; f < 2; ++f)
      #pragma unroll
      for (int ks = 0; ks < 2; ++ks) {
        const float* wsrc = fw + ((wm * 2 + f) * 16 + l15) * 64 + ks * 32 + l4 * 8;
        float4 wa = *(const float4*)wsrc;
        float4 wb = *(const float4*)(wsrc + 4);
        short8 w8;
        w8[0] = (short)f2bf(wa.x); w8[1] = (short)f2bf(wa.y);
        w8[2] = (short)f2bf(wa.z); w8[3] = (short)f2bf(wa.w);
        w8[4] = (short)f2bf(wb.x); w8[5] = (short)f2bf(wb.y);
        w8[6] = (short)f2bf(wb.z); w8[7] = (short)f2bf(wb.w);
        afr[f][ks] = w8;
      }
    f32x4 a2[3][2][4] = {};
    #pragma unroll
    for (int bt = 0; bt < 3; ++bt)
      #pragma unroll
      for (int ks = 0; ks < 2; ++ks)
        #pragma unroll
        for (int nf = 0; nf < 4; ++nf) {
          const int nl = wn * 16 + nf * 64 + l15;
          int byte = bt * 32768 + nl * 128 + (ks * 32 + l4 * 8) * 2;
          byte ^= ((nl & 7) << 4);
          short8 bfr = LD8(lp + byte);
          #pragma unroll
          for (int f = 0; f < 2; ++f)
            a2[bt][f][nf] = __builtin_amdgcn_mfma_f32_16x16x32_bf16(afr[f][ks], bfr, a2[bt][f][nf], 0, 0, 0);
        }
    #pragma unroll
    for (int bt = 0; bt < 3; ++bt)
      #pragma unroll
      for (int f = 0; f < 2; ++f)
        #pragma unroll
        for (int nf = 0; nf < 4; ++nf) {
          const int n = n0 + wn * 16 + nf * 64 + l15;
          const int o2b = (wm * 2 + f) * 16 + l4 * 4;
          float4 fb4 = *(const float4*)&fb[o2b];
          const size_t btg = (size_t)(gb * 12 + tloc + bt);
          float4 v;
          v.x = a2[bt][f][nf][0] + fb4.x;
          v.y = a2[bt][f][nf][1] + fb4.y;
          v.z = a2[bt][f][nf][2] + fb4.z;
          v.w = a2[bt][f][nf][3] + fb4.w;
          *(float4*)&outf[(btg * 1024 + n) * 64 + o2b] = v;
        }
  }
}

extern "C" void kernel_launch(void* const* d_in, const int* in_sizes, int n_in,
                              void* d_out, int out_size, void* d_ws, size_t ws_size,
                              hipStream_t stream) {
  const float* x   = (const float*)d_in[0];
  const float* Lk  = (const float*)d_in[1];
  const float* th1 = (const float*)d_in[2];
  const float* b1  = (const float*)d_in[3];
  const float* th2 = (const float*)d_in[4];
  const float* b2  = (const float*)d_in[5];
  const float* fcw = (const float*)d_in[6];
  const float* fcb = (const float*)d_in[7];

  char* ws = (char*)d_ws;
  size_t off = 0;
  auto alloc = [&](size_t bytes) { size_t p = off; off += (bytes + 255) & ~(size_t)255; return p; };
  size_t oBt = alloc((size_t)KC_ * N_ * 2);            // 6.29 MB
  size_t oTh = alloc((size_t)2 * 3 * 64 * 64 * 2);     // 48 KB
  size_t oX1 = alloc((size_t)B_ * C_ * T_ * N_ * 2);   // 50.3 MB (x1 scratch)
  size_t perY = (size_t)RPB * KC_ * 2;                 // 4.72 MB per batch per Y buffer
  size_t avail = ws_size > off ? ws_size - off : 0;
  int NB = (int)(avail / (2 * perY));                  // two Y buffers
  if (NB > 16) NB = 16;   // r14: cap chunk so each Y buffer (75.5 MB) stays L3-resident
  if (NB < 1) NB = 1;

  ushort_t* Bt  = (ushort_t*)(ws + oBt);
  ushort_t* Th  = (ushort_t*)(ws + oTh);
  ushort_t* X1  = (ushort_t*)(ws + oX1);
  ushort_t* Yb1 = (ushort_t*)(ws + off);
  ushort_t* Yb2 = Yb1 + (size_t)NB * RPB * KC_;

  prep_th<<<96, 256, 0, stream>>>(th1, th2, Th);
  prep_bt<<<1536, 256, 0, stream>>>(Lk, Bt);

  for (int b0 = 0; b0 < B_; b0 += NB) {
    int nb = (b0 + NB <= B_) ? NB : (B_ - b0);
    // layer-1 mix: x -> Y1
    mix_mfma<<<nb * 48, 256, 0, stream>>>(x, Th, Yb1, b0);
    // layer-1 gemm + fused mix2: Y1 -> x1 (ws) + Y2
    gemm8p<0><<<dim3(16 * nb), 512, 0, stream>>>(
        Yb1, Bt, (const void*)x, b1, X1, (const void*)(Th + 12288), fcb, (void*)Yb2, b0);
    // layer-2 gemm + fused fc: Y2 -> out (x2 never materialized)
    gemm8p<1><<<dim3(16 * nb), 512, 0, stream>>>(
        Yb2, Bt, (const void*)X1, b2, X1, (const void*)fcw, fcb, d_out, b0);
  }
}